// Round 6
// baseline (368.472 us; speedup 1.0000x reference)
//
#include <hip/hip_runtime.h>
#include <hip/hip_bf16.h>

// Sggnn_gcn — fused 2x(Linear512+BN+LReLU) + Wc projection, then GCN on 2-wide
// features. Restructuring: (w_norm^T @ t) @ Wc^T == w_norm^T @ (t @ Wc^T).
// v6: barrier-free K-loops. Both MFMA operands load global->register per lane
// (W from canonical bf16 copy in ws, L2-resident; A with f32->bf16 cvt in reg).
// Only the layer1->layer2 handoff tile T1s lives in LDS (64 KB) -> 2 blocks/CU.
// MFMA operands are SWAPPED (mfma(W,A)) so acc reg-index walks output columns:
// epilogue packs 4 adjacent cols -> ds_write_b64, killing the round-5 bank
// conflicts (1e7/dispatch) from scalar b16 stores.

typedef __hip_bfloat16 bf16_t;
typedef __bf16 bf16x8 __attribute__((ext_vector_type(8)));
typedef __bf16 bf16x4 __attribute__((ext_vector_type(4)));
typedef float f32x4 __attribute__((ext_vector_type(4)));

#define KDIM 512
#define BM 64      // rows per block

// load element i of a logically-f32 vector that may be stored as bf16
__device__ __forceinline__ float ldsel(const void* p, int i, int isbf) {
    return isbf ? __bfloat162float(((const bf16_t*)p)[i]) : ((const float*)p)[i];
}

// ---- probe: detect dtype of d (bf16 vs f32) from exponent statistics ----
__global__ void probe_kernel(const void* __restrict__ d, int* __restrict__ flag) {
    const unsigned short* u = (const unsigned short*)d;
    const int l = threadIdx.x;   // 64
    int cnt = 0;
    for (int i = l; i < 256; i += 64) {
        const int e = (u[i] >> 7) & 0xFF;
        cnt += (e >= 118 && e <= 129) ? 1 : 0;
    }
    #pragma unroll
    for (int off = 32; off; off >>= 1) cnt += __shfl_down(cnt, off, 64);
    if (l == 0) *flag = (cnt >= 200) ? 1 : 0;   // bf16 ~255, f32 ~134
}

// ---- prep: rowsum of adj = w + I  ->  d_inv_sqrt ----
__global__ void rowsum_kernel(const void* __restrict__ w, const int* __restrict__ flagp,
                              float* __restrict__ dinv) {
    const int isbf = *flagp;
    const int i = blockIdx.x;
    const int l = threadIdx.x;
    float s = 0.f;
    for (int j = l; j < 512; j += 64) s += ldsel(w, i * 512 + j, isbf);
    #pragma unroll
    for (int off = 32; off; off >>= 1) s += __shfl_down(s, off, 64);
    if (l == 0) dinv[i] = 1.0f / sqrtf(s + 1.0f);
}

// ---- prep: fold BN -> scale/shift; canonicalize Wc, bc to f32 ----
__global__ void params_kernel(const void* g1, const void* b1, const void* m1,
                              const void* v1, const void* be1,
                              const void* g2, const void* b2, const void* m2,
                              const void* v2, const void* be2,
                              const void* Wc, const void* bc,
                              const int* __restrict__ flagp,
                              float* sc1, float* sh1, float* sc2, float* sh2,
                              float* wcf, float* bcf) {
    const int isbf = *flagp;
    const int i = threadIdx.x;  // 512
    float s1 = ldsel(g1, i, isbf) / sqrtf(ldsel(v1, i, isbf) + 1e-5f);
    sc1[i] = s1;
    sh1[i] = (ldsel(b1, i, isbf) - ldsel(m1, i, isbf)) * s1 + ldsel(be1, i, isbf);
    float s2 = ldsel(g2, i, isbf) / sqrtf(ldsel(v2, i, isbf) + 1e-5f);
    sc2[i] = s2;
    sh2[i] = (ldsel(b2, i, isbf) - ldsel(m2, i, isbf)) * s2 + ldsel(be2, i, isbf);
    wcf[i] = ldsel(Wc, i, isbf);
    wcf[512 + i] = ldsel(Wc, 512 + i, isbf);
    if (i < 2) bcf[i] = ldsel(bc, i, isbf);
}

// ---- prep: canonicalize W1, W2 to linear bf16 ----
__global__ void wconv_kernel(const void* __restrict__ W1, const void* __restrict__ W2,
                             const int* __restrict__ flagp,
                             bf16_t* __restrict__ W1b, bf16_t* __restrict__ W2b) {
    const int isbf = *flagp;
    const int i = blockIdx.x * 256 + threadIdx.x;   // 262144
    W1b[i] = __float2bfloat16(ldsel(W1, i, isbf));
    W2b[i] = __float2bfloat16(ldsel(W2, i, isbf));
}

// ---- prep: wn_t[n][m] = w_norm[m][n] ----
__global__ void wnorm_kernel(const void* __restrict__ w, const int* __restrict__ flagp,
                             const float* __restrict__ dinv, float* __restrict__ wn_t) {
    const int isbf = *flagp;
    const int idx = blockIdx.x * 256 + threadIdx.x;   // 262144
    const int n = idx >> 9, m = idx & 511;
    float a = ldsel(w, n * 512 + m, isbf) + (m == n ? 1.0f : 0.0f);
    wn_t[idx] = a * dinv[m] * dinv[n];
}

// ---- fused MLP: 8 waves, 64-row stripe; operands global->reg, no k-loop LDS ----
__launch_bounds__(512, 2)
__global__ void fused_mlp(const void* __restrict__ A,      // d: f32 or bf16, 65536x512
                          const bf16_t* __restrict__ W1b,  // linear bf16 512x512
                          const bf16_t* __restrict__ W2b,
                          const float* __restrict__ sc1, const float* __restrict__ sh1,
                          const float* __restrict__ sc2, const float* __restrict__ sh2,
                          const float* __restrict__ wcf,   // 1024 f32
                          const int* __restrict__ flagp,
                          float* __restrict__ U)           // 65536 x 2
{
    __shared__ __align__(16) bf16_t T1s[BM * KDIM];   // 64 KB, XOR-swizzled rows
    __shared__ float Ured[4][BM][2];                  // 2 KB

    const int isbf = *flagp;
    const int tid = threadIdx.x;
    const int wave = tid >> 6, lane = tid & 63;
    const int bm = blockIdx.x;                 // 0..1023
    const int wr = wave >> 2, wc = wave & 3;   // wave: rows wr*32..+32, cols wc*128..+128
    const int rl = lane & 15, hi = lane >> 4;

    // per-lane fragment bases (row rl of the 16-row group, k-chunk hi*8)
    const bf16_t* Wp1 = W1b + (wc * 128 + rl) * KDIM + hi * 8;
    const bf16_t* Wp2 = W2b + (wc * 128 + rl) * KDIM + hi * 8;
    const size_t arow = (size_t)(bm * BM + wr * 32 + rl) * KDIM + hi * 8;
    const bf16_t* Ab = (const bf16_t*)A + arow;
    const float*  Af = (const float*)A + arow;

    // acc[j][i]: mfma(W_frag j, A_frag i) -> D row = W-row (out col), D col = A-row
    f32x4 acc[8][2] = {};

    // ================= phase 1: T1 = lrelu(bn1(A @ W1^T)) =================
    for (int kt = 0; kt < 16; ++kt) {
        bf16x8 bfr[8];
        #pragma unroll
        for (int j = 0; j < 8; ++j)
            bfr[j] = *reinterpret_cast<const bf16x8*>(Wp1 + j * 16 * KDIM + kt * 32);
        bf16x8 af[2];
        #pragma unroll
        for (int i = 0; i < 2; ++i) {
            if (isbf) {
                af[i] = *reinterpret_cast<const bf16x8*>(Ab + i * 16 * KDIM + kt * 32);
            } else {
                const f32x4* ap = (const f32x4*)(Af + i * 16 * KDIM + kt * 32);
                const f32x4 a0 = ap[0], a1 = ap[1];
                bf16x8 v;
                v[0] = (__bf16)a0.x; v[1] = (__bf16)a0.y; v[2] = (__bf16)a0.z; v[3] = (__bf16)a0.w;
                v[4] = (__bf16)a1.x; v[5] = (__bf16)a1.y; v[6] = (__bf16)a1.z; v[7] = (__bf16)a1.w;
                af[i] = v;
            }
        }
        #pragma unroll
        for (int j = 0; j < 8; ++j)
            #pragma unroll
            for (int i = 0; i < 2; ++i)
                acc[j][i] = __builtin_amdgcn_mfma_f32_16x16x32_bf16(bfr[j], af[i], acc[j][i], 0, 0, 0);
    }

    // epilogue 1: BN + LReLU; lane holds 4 ADJACENT out-cols -> b64 store
    #pragma unroll
    for (int j = 0; j < 8; ++j) {
        const int gcol0 = wc * 128 + j * 16 + hi * 4;
        const f32x4 s4 = *reinterpret_cast<const f32x4*>(&sc1[gcol0]);
        const f32x4 h4 = *reinterpret_cast<const f32x4*>(&sh1[gcol0]);
        #pragma unroll
        for (int i = 0; i < 2; ++i) {
            const int row = wr * 32 + i * 16 + rl;
            int off = (row << 10) + (gcol0 << 1);
            off ^= (row & 7) << 4;
            bf16x4 pk;
            #pragma unroll
            for (int r = 0; r < 4; ++r) {
                float y = acc[j][i][r] * s4[r] + h4[r];
                y = y > 0.f ? y : 0.1f * y;
                pk[r] = (__bf16)y;
            }
            *reinterpret_cast<bf16x4*>((char*)T1s + off) = pk;
        }
    }
    __syncthreads();

    // ================= phase 2: Y2 = lrelu(bn2(T1 @ W2^T)); U = Y2 @ Wc^T =================
    #pragma unroll
    for (int j = 0; j < 8; ++j)
        #pragma unroll
        for (int i = 0; i < 2; ++i)
            acc[j][i] = f32x4{0.f, 0.f, 0.f, 0.f};

    for (int kt = 0; kt < 16; ++kt) {
        bf16x8 bfr[8];
        #pragma unroll
        for (int j = 0; j < 8; ++j)
            bfr[j] = *reinterpret_cast<const bf16x8*>(Wp2 + j * 16 * KDIM + kt * 32);
        bf16x8 af[2];
        #pragma unroll
        for (int i = 0; i < 2; ++i) {
            const int row = wr * 32 + i * 16 + rl;
            int off = (row << 10) + kt * 64 + hi * 16;
            off ^= (row & 7) << 4;
            af[i] = *reinterpret_cast<const bf16x8*>((const char*)T1s + off);
        }
        #pragma unroll
        for (int j = 0; j < 8; ++j)
            #pragma unroll
            for (int i = 0; i < 2; ++i)
                acc[j][i] = __builtin_amdgcn_mfma_f32_16x16x32_bf16(bfr[j], af[i], acc[j][i], 0, 0, 0);
    }

    // epilogue 2: BN + LReLU + 512->2 projection (in-lane over j,r; shfl over hi)
    float p0[2] = {0.f, 0.f}, p1[2] = {0.f, 0.f};
    #pragma unroll
    for (int j = 0; j < 8; ++j) {
        const int gcol0 = wc * 128 + j * 16 + hi * 4;
        const f32x4 s4 = *reinterpret_cast<const f32x4*>(&sc2[gcol0]);
        const f32x4 h4 = *reinterpret_cast<const f32x4*>(&sh2[gcol0]);
        const f32x4 w0 = *reinterpret_cast<const f32x4*>(&wcf[gcol0]);
        const f32x4 w1 = *reinterpret_cast<const f32x4*>(&wcf[512 + gcol0]);
        #pragma unroll
        for (int i = 0; i < 2; ++i)
            #pragma unroll
            for (int r = 0; r < 4; ++r) {
                float y = acc[j][i][r] * s4[r] + h4[r];
                y = y > 0.f ? y : 0.1f * y;
                p0[i] += y * w0[r];
                p1[i] += y * w1[r];
            }
    }
    #pragma unroll
    for (int i = 0; i < 2; ++i) {
        float a = p0[i], b = p1[i];
        a += __shfl_xor(a, 16, 64);  b += __shfl_xor(b, 16, 64);
        a += __shfl_xor(a, 32, 64);  b += __shfl_xor(b, 32, 64);
        if (hi == 0) {
            const int row = wr * 32 + i * 16 + rl;
            Ured[wc][row][0] = a;
            Ured[wc][row][1] = b;
        }
    }
    __syncthreads();
    if (tid < BM * 2) {
        const int row = tid >> 1, c = tid & 1;
        U[(size_t)(bm * BM + row) * 2 + c] =
            Ured[0][row][c] + Ured[1][row][c] + Ured[2][row][c] + Ured[3][row][c];
    }
}

// ---- GCN on 2-wide features ----
__global__ void gcn_kernel(const float* __restrict__ wn_t, const float* __restrict__ U,
                           const float* __restrict__ bcf, const int* __restrict__ flagp,
                           void* __restrict__ out) {
    const int isbf = *flagp;
    const int wave = threadIdx.x >> 6, lane = threadIdx.x & 63;
    const int task = blockIdx.x * 4 + wave;   // (b, n)
    const int b = task >> 9, n = task & 511;
    const float* wrow = wn_t + n * 512;
    const float* ub = U + b * 1024;
    float a0 = 0.f, a1 = 0.f;
    for (int m = lane; m < 512; m += 64) {
        const float wv = wrow[m];
        a0 += wv * ub[m * 2];
        a1 += wv * ub[m * 2 + 1];
    }
    #pragma unroll
    for (int off = 32; off; off >>= 1) {
        a0 += __shfl_down(a0, off, 64);
        a1 += __shfl_down(a1, off, 64);
    }
    if (lane == 0) {
        const float r0 = a0 + bcf[0];
        const float r1 = a1 + bcf[1];
        if (isbf) {
            ((bf16_t*)out)[task * 2]     = __float2bfloat16(r0);
            ((bf16_t*)out)[task * 2 + 1] = __float2bfloat16(r1);
        } else {
            ((float*)out)[task * 2]     = r0;
            ((float*)out)[task * 2 + 1] = r1;
        }
    }
}

extern "C" void kernel_launch(void* const* d_in, const int* in_sizes, int n_in,
                              void* d_out, int out_size, void* d_ws, size_t ws_size,
                              hipStream_t stream) {
    const void* d   = d_in[0];
    const void* w   = d_in[1];
    const void* W1  = d_in[2];
    const void* b1  = d_in[3];
    const void* g1  = d_in[4];
    const void* be1 = d_in[5];
    const void* m1  = d_in[6];
    const void* v1  = d_in[7];
    const void* W2  = d_in[8];
    const void* b2  = d_in[9];
    const void* g2  = d_in[10];
    const void* be2 = d_in[11];
    const void* m2  = d_in[12];
    const void* v2  = d_in[13];
    const void* Wc  = d_in[14];
    const void* bc  = d_in[15];

    // workspace layout (~2.6 MB total)
    char* ws = (char*)d_ws;
    float*  wn_t = (float*)ws;                         // 1 MB
    bf16_t* W1b  = (bf16_t*)(ws + 0x100000);           // 512 KB (linear bf16)
    bf16_t* W2b  = (bf16_t*)(ws + 0x180000);           // 512 KB
    float*  sc1  = (float*)(ws + 0x200000);
    float*  sh1  = sc1 + 512;
    float*  sc2  = sh1 + 512;
    float*  sh2  = sc2 + 512;
    float*  dinv = sh2 + 512;
    float*  wcf  = (float*)(ws + 0x204000);            // 4 KB
    float*  bcf  = (float*)(ws + 0x205000);
    int*    flag = (int*)(ws + 0x205100);
    float*  U    = (float*)(ws + 0x208000);            // 512 KB

    const int M = 128 * 512;   // 65536 rows

    probe_kernel<<<1, 64, 0, stream>>>(d, flag);
    rowsum_kernel<<<512, 64, 0, stream>>>(w, flag, dinv);
    params_kernel<<<1, 512, 0, stream>>>(g1, b1, m1, v1, be1, g2, b2, m2, v2, be2,
                                         Wc, bc, flag, sc1, sh1, sc2, sh2, wcf, bcf);
    wconv_kernel<<<1024, 256, 0, stream>>>(W1, W2, flag, W1b, W2b);
    wnorm_kernel<<<1024, 256, 0, stream>>>(w, flag, dinv, wn_t);

    fused_mlp<<<M / BM, 512, 0, stream>>>(d, W1b, W2b, sc1, sh1, sc2, sh2, wcf, flag, U);

    gcn_kernel<<<M / 4, 256, 0, stream>>>(wn_t, U, bcf, flag, d_out);
}

// Round 7
// 286.139 us; speedup vs baseline: 1.2877x; 1.2877x over previous
//
#include <hip/hip_runtime.h>
#include <hip/hip_bf16.h>

// Sggnn_gcn — fused 2x(Linear512+BN+LReLU) + Wc projection, then GCN on 2-wide
// features. Restructuring: (w_norm^T @ t) @ Wc^T == w_norm^T @ (t @ Wc^T).
// v7: barrier-free K-loops (v6) + FRAGMENT-MAJOR packed operands so every
// global load is coalesced (v6's regression was row-gather fragment loads:
// MfmaUtil 8%, 240 GB/s effective). A is packed once by aconv (LDS transpose);
// W1/W2 packed by wconv. 256-thread blocks, 33 KB LDS -> 4 blocks/CU.

typedef __hip_bfloat16 bf16_t;
typedef __bf16 bf16x8 __attribute__((ext_vector_type(8)));
typedef __bf16 bf16x4 __attribute__((ext_vector_type(4)));
typedef float f32x4 __attribute__((ext_vector_type(4)));

#define KDIM 512
#define BM 32      // rows per block

// load element i of a logically-f32 vector that may be stored as bf16
__device__ __forceinline__ float ldsel(const void* p, int i, int isbf) {
    return isbf ? __bfloat162float(((const bf16_t*)p)[i]) : ((const float*)p)[i];
}

// ---- probe: detect dtype of d (bf16 vs f32) from exponent statistics ----
__global__ void probe_kernel(const void* __restrict__ d, int* __restrict__ flag) {
    const unsigned short* u = (const unsigned short*)d;
    const int l = threadIdx.x;   // 64
    int cnt = 0;
    for (int i = l; i < 256; i += 64) {
        const int e = (u[i] >> 7) & 0xFF;
        cnt += (e >= 118 && e <= 129) ? 1 : 0;
    }
    #pragma unroll
    for (int off = 32; off; off >>= 1) cnt += __shfl_down(cnt, off, 64);
    if (l == 0) *flag = (cnt >= 200) ? 1 : 0;   // bf16 ~255, f32 ~134
}

// ---- prep: rowsum of adj = w + I  ->  d_inv_sqrt ----
__global__ void rowsum_kernel(const void* __restrict__ w, const int* __restrict__ flagp,
                              float* __restrict__ dinv) {
    const int isbf = *flagp;
    const int i = blockIdx.x;
    const int l = threadIdx.x;
    float s = 0.f;
    for (int j = l; j < 512; j += 64) s += ldsel(w, i * 512 + j, isbf);
    #pragma unroll
    for (int off = 32; off; off >>= 1) s += __shfl_down(s, off, 64);
    if (l == 0) dinv[i] = 1.0f / sqrtf(s + 1.0f);
}

// ---- prep: fold BN -> scale/shift; canonicalize Wc, bc to f32 ----
__global__ void params_kernel(const void* g1, const void* b1, const void* m1,
                              const void* v1, const void* be1,
                              const void* g2, const void* b2, const void* m2,
                              const void* v2, const void* be2,
                              const void* Wc, const void* bc,
                              const int* __restrict__ flagp,
                              float* sc1, float* sh1, float* sc2, float* sh2,
                              float* wcf, float* bcf) {
    const int isbf = *flagp;
    const int i = threadIdx.x;  // 512
    float s1 = ldsel(g1, i, isbf) / sqrtf(ldsel(v1, i, isbf) + 1e-5f);
    sc1[i] = s1;
    sh1[i] = (ldsel(b1, i, isbf) - ldsel(m1, i, isbf)) * s1 + ldsel(be1, i, isbf);
    float s2 = ldsel(g2, i, isbf) / sqrtf(ldsel(v2, i, isbf) + 1e-5f);
    sc2[i] = s2;
    sh2[i] = (ldsel(b2, i, isbf) - ldsel(m2, i, isbf)) * s2 + ldsel(be2, i, isbf);
    wcf[i] = ldsel(Wc, i, isbf);
    wcf[512 + i] = ldsel(Wc, 512 + i, isbf);
    if (i < 2) bcf[i] = ldsel(bc, i, isbf);
}

// ---- prep: W1,W2 -> bf16 in FRAGMENT-MAJOR order.
// chunk t = ((c16*16 + kt)*64 + lane); data = W[c16*16 + (lane&15)][kt*32 + (lane>>4)*8 ..+8]
__global__ void wconv_kernel(const void* __restrict__ W1, const void* __restrict__ W2,
                             const int* __restrict__ flagp,
                             bf16_t* __restrict__ W1pk, bf16_t* __restrict__ W2pk) {
    const int isbf = *flagp;
    const int t = blockIdx.x * 256 + threadIdx.x;   // 0..32767
    const int lane = t & 63;
    const int kt = (t >> 6) & 15;
    const int c16 = t >> 10;
    const int src = (c16 * 16 + (lane & 15)) * 512 + kt * 32 + (lane >> 4) * 8;
    bf16x8 v1, v2;
    #pragma unroll
    for (int e = 0; e < 8; ++e) {
        v1[e] = (__bf16)ldsel(W1, src + e, isbf);
        v2[e] = (__bf16)ldsel(W2, src + e, isbf);
    }
    *reinterpret_cast<bf16x8*>(W1pk + (size_t)t * 8) = v1;
    *reinterpret_cast<bf16x8*>(W2pk + (size_t)t * 8) = v2;
}

// ---- prep: A -> bf16 fragment-major via LDS transpose (coalesced both sides).
// Apk chunk ((g*16 + kt)*64 + lane) = A[g*16 + (lane&15)][kt*32 + (lane>>4)*8 ..+8]
__global__ void aconv_kernel(const void* __restrict__ A, const int* __restrict__ flagp,
                             bf16_t* __restrict__ Apk) {
    __shared__ float As[16][516];   // pad 4 -> 2-way-max bank aliasing on pack reads
    const int isbf = *flagp;
    const int t = threadIdx.x;      // 256
    const int g = blockIdx.x;       // 0..4095; rows g*16..+16
    if (isbf) {
        const bf16_t* Ab = (const bf16_t*)A + (size_t)g * 16 * 512;
        #pragma unroll
        for (int p = 0; p < 4; ++p) {
            const int c = p * 256 + t;          // 1024 chunks of 8 bf16
            const int row = c >> 6, col8 = c & 63;
            bf16x8 v = *reinterpret_cast<const bf16x8*>(Ab + row * 512 + col8 * 8);
            f32x4 f0, f1;
            f0.x = (float)v[0]; f0.y = (float)v[1]; f0.z = (float)v[2]; f0.w = (float)v[3];
            f1.x = (float)v[4]; f1.y = (float)v[5]; f1.z = (float)v[6]; f1.w = (float)v[7];
            *reinterpret_cast<f32x4*>(&As[row][col8 * 8])     = f0;
            *reinterpret_cast<f32x4*>(&As[row][col8 * 8 + 4]) = f1;
        }
    } else {
        const float* Af = (const float*)A + (size_t)g * 16 * 512;
        #pragma unroll
        for (int p = 0; p < 8; ++p) {
            const int c = p * 256 + t;          // 2048 chunks of 4 f32
            const int row = c >> 7, col4 = c & 127;
            f32x4 v = *reinterpret_cast<const f32x4*>(Af + row * 512 + col4 * 4);
            *reinterpret_cast<f32x4*>(&As[row][col4 * 4]) = v;
        }
    }
    __syncthreads();
    #pragma unroll
    for (int p = 0; p < 4; ++p) {
        const int c = p * 256 + t;              // 1024 chunks: kt x lane
        const int kt = c >> 6, lane = c & 63;
        const float* src = &As[lane & 15][kt * 32 + (lane >> 4) * 8];
        const f32x4 a0 = *reinterpret_cast<const f32x4*>(src);
        const f32x4 a1 = *reinterpret_cast<const f32x4*>(src + 4);
        bf16x8 v;
        v[0] = (__bf16)a0.x; v[1] = (__bf16)a0.y; v[2] = (__bf16)a0.z; v[3] = (__bf16)a0.w;
        v[4] = (__bf16)a1.x; v[5] = (__bf16)a1.y; v[6] = (__bf16)a1.z; v[7] = (__bf16)a1.w;
        *reinterpret_cast<bf16x8*>(Apk + ((size_t)(g * 16 + kt) * 64 + lane) * 8) = v;
    }
}

// ---- prep: wn_t[n][m] = w_norm[m][n] ----
__global__ void wnorm_kernel(const void* __restrict__ w, const int* __restrict__ flagp,
                             const float* __restrict__ dinv, float* __restrict__ wn_t) {
    const int isbf = *flagp;
    const int idx = blockIdx.x * 256 + threadIdx.x;   // 262144
    const int n = idx >> 9, m = idx & 511;
    float a = ldsel(w, n * 512 + m, isbf) + (m == n ? 1.0f : 0.0f);
    wn_t[idx] = a * dinv[m] * dinv[n];
}

// ---- fused MLP: 4 waves, 32-row stripe; all operands coalesced global->reg ----
template <int PACKED>
__launch_bounds__(256, 4)
__global__ void fused_mlp(const void* __restrict__ A,      // raw d (fallback path)
                          const bf16_t* __restrict__ Apk,  // fragment-major bf16
                          const bf16_t* __restrict__ W1pk,
                          const bf16_t* __restrict__ W2pk,
                          const float* __restrict__ sc1, const float* __restrict__ sh1,
                          const float* __restrict__ sc2, const float* __restrict__ sh2,
                          const float* __restrict__ wcf,   // 1024 f32
                          const int* __restrict__ flagp,
                          float* __restrict__ U)           // 65536 x 2
{
    __shared__ __align__(16) bf16_t T1s[BM * KDIM];   // 32 KB, XOR-swizzled rows
    __shared__ float Ured[4][BM][2];                  // 1 KB

    const int isbf = *flagp;
    const int tid = threadIdx.x;
    const int wc = tid >> 6, lane = tid & 63;  // wave wc: cols wc*128..+128, rows 0..31
    const int bm = blockIdx.x;                 // 0..2047; rows bm*32..+32
    const int rl = lane & 15, hi = lane >> 4;

    // acc[j][i] = mfma(W_frag j, A_frag i): D row = out col, D col = A row
    f32x4 acc[8][2] = {};

    // ================= phase 1: T1 = lrelu(bn1(A @ W1^T)) =================
    for (int kt = 0; kt < 16; ++kt) {
        bf16x8 bfr[8], af[2];
        #pragma unroll
        for (int j = 0; j < 8; ++j)
            bfr[j] = *reinterpret_cast<const bf16x8*>(
                W1pk + ((size_t)((wc * 8 + j) * 16 + kt) * 64 + lane) * 8);
        #pragma unroll
        for (int i = 0; i < 2; ++i) {
            if (PACKED) {
                af[i] = *reinterpret_cast<const bf16x8*>(
                    Apk + ((size_t)((bm * 2 + i) * 16 + kt) * 64 + lane) * 8);
            } else {
                const size_t arow = (size_t)(bm * BM + i * 16 + rl) * KDIM + hi * 8 + kt * 32;
                if (isbf) {
                    af[i] = *reinterpret_cast<const bf16x8*>((const bf16_t*)A + arow);
                } else {
                    const f32x4* ap = (const f32x4*)((const float*)A + arow);
                    const f32x4 a0 = ap[0], a1 = ap[1];
                    bf16x8 v;
                    v[0] = (__bf16)a0.x; v[1] = (__bf16)a0.y; v[2] = (__bf16)a0.z; v[3] = (__bf16)a0.w;
                    v[4] = (__bf16)a1.x; v[5] = (__bf16)a1.y; v[6] = (__bf16)a1.z; v[7] = (__bf16)a1.w;
                    af[i] = v;
                }
            }
        }
        #pragma unroll
        for (int j = 0; j < 8; ++j)
            #pragma unroll
            for (int i = 0; i < 2; ++i)
                acc[j][i] = __builtin_amdgcn_mfma_f32_16x16x32_bf16(bfr[j], af[i], acc[j][i], 0, 0, 0);
    }

    // epilogue 1: BN + LReLU; lane holds 4 ADJACENT out-cols -> b64 store
    #pragma unroll
    for (int j = 0; j < 8; ++j) {
        const int gcol0 = wc * 128 + j * 16 + hi * 4;
        const f32x4 s4 = *reinterpret_cast<const f32x4*>(&sc1[gcol0]);
        const f32x4 h4 = *reinterpret_cast<const f32x4*>(&sh1[gcol0]);
        #pragma unroll
        for (int i = 0; i < 2; ++i) {
            const int row = i * 16 + rl;
            int off = (row << 10) + (gcol0 << 1);
            off ^= (row & 7) << 4;
            bf16x4 pk;
            #pragma unroll
            for (int r = 0; r < 4; ++r) {
                float y = acc[j][i][r] * s4[r] + h4[r];
                y = y > 0.f ? y : 0.1f * y;
                pk[r] = (__bf16)y;
            }
            *reinterpret_cast<bf16x4*>((char*)T1s + off) = pk;
        }
    }
    __syncthreads();

    // ================= phase 2: Y2 = lrelu(bn2(T1 @ W2^T)); U = Y2 @ Wc^T =================
    #pragma unroll
    for (int j = 0; j < 8; ++j)
        #pragma unroll
        for (int i = 0; i < 2; ++i)
            acc[j][i] = f32x4{0.f, 0.f, 0.f, 0.f};

    for (int kt = 0; kt < 16; ++kt) {
        bf16x8 bfr[8], af[2];
        #pragma unroll
        for (int j = 0; j < 8; ++j)
            bfr[j] = *reinterpret_cast<const bf16x8*>(
                W2pk + ((size_t)((wc * 8 + j) * 16 + kt) * 64 + lane) * 8);
        #pragma unroll
        for (int i = 0; i < 2; ++i) {
            const int row = i * 16 + rl;
            int off = (row << 10) + kt * 64 + hi * 16;
            off ^= (row & 7) << 4;
            af[i] = *reinterpret_cast<const bf16x8*>((const char*)T1s + off);
        }
        #pragma unroll
        for (int j = 0; j < 8; ++j)
            #pragma unroll
            for (int i = 0; i < 2; ++i)
                acc[j][i] = __builtin_amdgcn_mfma_f32_16x16x32_bf16(bfr[j], af[i], acc[j][i], 0, 0, 0);
    }

    // epilogue 2: BN + LReLU + 512->2 projection (in-lane over j,r; shfl over hi)
    float p0[2] = {0.f, 0.f}, p1[2] = {0.f, 0.f};
    #pragma unroll
    for (int j = 0; j < 8; ++j) {
        const int gcol0 = wc * 128 + j * 16 + hi * 4;
        const f32x4 s4 = *reinterpret_cast<const f32x4*>(&sc2[gcol0]);
        const f32x4 h4 = *reinterpret_cast<const f32x4*>(&sh2[gcol0]);
        const f32x4 w0 = *reinterpret_cast<const f32x4*>(&wcf[gcol0]);
        const f32x4 w1 = *reinterpret_cast<const f32x4*>(&wcf[512 + gcol0]);
        #pragma unroll
        for (int i = 0; i < 2; ++i)
            #pragma unroll
            for (int r = 0; r < 4; ++r) {
                float y = acc[j][i][r] * s4[r] + h4[r];
                y = y > 0.f ? y : 0.1f * y;
                p0[i] += y * w0[r];
                p1[i] += y * w1[r];
            }
    }
    #pragma unroll
    for (int i = 0; i < 2; ++i) {
        float a = p0[i], b = p1[i];
        a += __shfl_xor(a, 16, 64);  b += __shfl_xor(b, 16, 64);
        a += __shfl_xor(a, 32, 64);  b += __shfl_xor(b, 32, 64);
        if (hi == 0) {
            const int row = i * 16 + rl;
            Ured[wc][row][0] = a;
            Ured[wc][row][1] = b;
        }
    }
    __syncthreads();
    if (tid < BM * 2) {
        const int row = tid >> 1, c = tid & 1;
        U[(size_t)(bm * BM + row) * 2 + c] =
            Ured[0][row][c] + Ured[1][row][c] + Ured[2][row][c] + Ured[3][row][c];
    }
}

// ---- GCN on 2-wide features ----
__global__ void gcn_kernel(const float* __restrict__ wn_t, const float* __restrict__ U,
                           const float* __restrict__ bcf, const int* __restrict__ flagp,
                           void* __restrict__ out) {
    const int isbf = *flagp;
    const int wave = threadIdx.x >> 6, lane = threadIdx.x & 63;
    const int task = blockIdx.x * 4 + wave;   // (b, n)
    const int b = task >> 9, n = task & 511;
    const float* wrow = wn_t + n * 512;
    const float* ub = U + b * 1024;
    float a0 = 0.f, a1 = 0.f;
    for (int m = lane; m < 512; m += 64) {
        const float wv = wrow[m];
        a0 += wv * ub[m * 2];
        a1 += wv * ub[m * 2 + 1];
    }
    #pragma unroll
    for (int off = 32; off; off >>= 1) {
        a0 += __shfl_down(a0, off, 64);
        a1 += __shfl_down(a1, off, 64);
    }
    if (lane == 0) {
        const float r0 = a0 + bcf[0];
        const float r1 = a1 + bcf[1];
        if (isbf) {
            ((bf16_t*)out)[task * 2]     = __float2bfloat16(r0);
            ((bf16_t*)out)[task * 2 + 1] = __float2bfloat16(r1);
        } else {
            ((float*)out)[task * 2]     = r0;
            ((float*)out)[task * 2 + 1] = r1;
        }
    }
}

extern "C" void kernel_launch(void* const* d_in, const int* in_sizes, int n_in,
                              void* d_out, int out_size, void* d_ws, size_t ws_size,
                              hipStream_t stream) {
    const void* d   = d_in[0];
    const void* w   = d_in[1];
    const void* W1  = d_in[2];
    const void* b1  = d_in[3];
    const void* g1  = d_in[4];
    const void* be1 = d_in[5];
    const void* m1  = d_in[6];
    const void* v1  = d_in[7];
    const void* W2  = d_in[8];
    const void* b2  = d_in[9];
    const void* g2  = d_in[10];
    const void* be2 = d_in[11];
    const void* m2  = d_in[12];
    const void* v2  = d_in[13];
    const void* Wc  = d_in[14];
    const void* bc  = d_in[15];

    // workspace layout: 3 MB small buffers + 64 MB Apk
    char* ws = (char*)d_ws;
    float*  wn_t = (float*)ws;                         // 1 MB
    bf16_t* W1pk = (bf16_t*)(ws + 0x100000);           // 512 KB (fragment-major)
    bf16_t* W2pk = (bf16_t*)(ws + 0x180000);           // 512 KB
    float*  sc1  = (float*)(ws + 0x200000);
    float*  sh1  = sc1 + 512;
    float*  sc2  = sh1 + 512;
    float*  sh2  = sc2 + 512;
    float*  dinv = sh2 + 512;
    float*  wcf  = (float*)(ws + 0x204000);            // 4 KB
    float*  bcf  = (float*)(ws + 0x205000);
    int*    flag = (int*)(ws + 0x205100);
    float*  U    = (float*)(ws + 0x208000);            // 512 KB
    bf16_t* Apk  = (bf16_t*)(ws + 0x300000);           // 64 MB (fragment-major A)

    const size_t NEED = 0x300000 + (size_t)65536 * 512 * sizeof(bf16_t);
    const bool packed = ws_size >= NEED;

    const int M = 128 * 512;   // 65536 rows

    probe_kernel<<<1, 64, 0, stream>>>(d, flag);
    rowsum_kernel<<<512, 64, 0, stream>>>(w, flag, dinv);
    params_kernel<<<1, 512, 0, stream>>>(g1, b1, m1, v1, be1, g2, b2, m2, v2, be2,
                                         Wc, bc, flag, sc1, sh1, sc2, sh2, wcf, bcf);
    wconv_kernel<<<128, 256, 0, stream>>>(W1, W2, flag, W1pk, W2pk);
    wnorm_kernel<<<1024, 256, 0, stream>>>(w, flag, dinv, wn_t);

    if (packed) {
        aconv_kernel<<<M / 16, 256, 0, stream>>>(d, flag, Apk);
        fused_mlp<1><<<M / BM, 256, 0, stream>>>(d, Apk, W1pk, W2pk,
                                                 sc1, sh1, sc2, sh2, wcf, flag, U);
    } else {
        fused_mlp<0><<<M / BM, 256, 0, stream>>>(d, Apk, W1pk, W2pk,
                                                 sc1, sh1, sc2, sh2, wcf, flag, U);
    }

    gcn_kernel<<<M / 4, 256, 0, stream>>>(wn_t, U, bcf, flag, d_out);
}

// Round 8
// 215.853 us; speedup vs baseline: 1.7070x; 1.3256x over previous
//
#include <hip/hip_runtime.h>
#include <hip/hip_bf16.h>

// Sggnn_gcn — fused 2x(Linear512+BN+LReLU) + Wc projection, then GCN on 2-wide
// features. Restructuring: (w_norm^T @ t) @ Wc^T == w_norm^T @ (t @ Wc^T).
// v8: v7's fragment-major packed coalesced loads, but wave tile 32x64
// (acc[4][2] = 32 AGPRs) to eliminate v7's register spills (VGPR=64 cap with
// acc[8][2]=64 AGPRs left nothing for operands -> 430 MB/dispatch scratch).
// 1024-thread blocks (16 waves = 2 row-groups x 8 col-groups), BM=64 so the
// per-block W read (1 MB) amortizes over 64 rows.

typedef __hip_bfloat16 bf16_t;
typedef __bf16 bf16x8 __attribute__((ext_vector_type(8)));
typedef __bf16 bf16x4 __attribute__((ext_vector_type(4)));
typedef float f32x4 __attribute__((ext_vector_type(4)));

#define KDIM 512
#define BM 64      // rows per block

// load element i of a logically-f32 vector that may be stored as bf16
__device__ __forceinline__ float ldsel(const void* p, int i, int isbf) {
    return isbf ? __bfloat162float(((const bf16_t*)p)[i]) : ((const float*)p)[i];
}

// ---- probe: detect dtype of d (bf16 vs f32) from exponent statistics ----
__global__ void probe_kernel(const void* __restrict__ d, int* __restrict__ flag) {
    const unsigned short* u = (const unsigned short*)d;
    const int l = threadIdx.x;   // 64
    int cnt = 0;
    for (int i = l; i < 256; i += 64) {
        const int e = (u[i] >> 7) & 0xFF;
        cnt += (e >= 118 && e <= 129) ? 1 : 0;
    }
    #pragma unroll
    for (int off = 32; off; off >>= 1) cnt += __shfl_down(cnt, off, 64);
    if (l == 0) *flag = (cnt >= 200) ? 1 : 0;   // bf16 ~255, f32 ~134
}

// ---- prep: rowsum of adj = w + I  ->  d_inv_sqrt ----
__global__ void rowsum_kernel(const void* __restrict__ w, const int* __restrict__ flagp,
                              float* __restrict__ dinv) {
    const int isbf = *flagp;
    const int i = blockIdx.x;
    const int l = threadIdx.x;
    float s = 0.f;
    for (int j = l; j < 512; j += 64) s += ldsel(w, i * 512 + j, isbf);
    #pragma unroll
    for (int off = 32; off; off >>= 1) s += __shfl_down(s, off, 64);
    if (l == 0) dinv[i] = 1.0f / sqrtf(s + 1.0f);
}

// ---- prep: fold BN -> scale/shift; canonicalize Wc, bc to f32 ----
__global__ void params_kernel(const void* g1, const void* b1, const void* m1,
                              const void* v1, const void* be1,
                              const void* g2, const void* b2, const void* m2,
                              const void* v2, const void* be2,
                              const void* Wc, const void* bc,
                              const int* __restrict__ flagp,
                              float* sc1, float* sh1, float* sc2, float* sh2,
                              float* wcf, float* bcf) {
    const int isbf = *flagp;
    const int i = threadIdx.x;  // 512
    float s1 = ldsel(g1, i, isbf) / sqrtf(ldsel(v1, i, isbf) + 1e-5f);
    sc1[i] = s1;
    sh1[i] = (ldsel(b1, i, isbf) - ldsel(m1, i, isbf)) * s1 + ldsel(be1, i, isbf);
    float s2 = ldsel(g2, i, isbf) / sqrtf(ldsel(v2, i, isbf) + 1e-5f);
    sc2[i] = s2;
    sh2[i] = (ldsel(b2, i, isbf) - ldsel(m2, i, isbf)) * s2 + ldsel(be2, i, isbf);
    wcf[i] = ldsel(Wc, i, isbf);
    wcf[512 + i] = ldsel(Wc, 512 + i, isbf);
    if (i < 2) bcf[i] = ldsel(bc, i, isbf);
}

// ---- prep: W1,W2 -> bf16 in FRAGMENT-MAJOR order.
// chunk t = ((c16*16 + kt)*64 + lane); data = W[c16*16 + (lane&15)][kt*32 + (lane>>4)*8 ..+8]
__global__ void wconv_kernel(const void* __restrict__ W1, const void* __restrict__ W2,
                             const int* __restrict__ flagp,
                             bf16_t* __restrict__ W1pk, bf16_t* __restrict__ W2pk) {
    const int isbf = *flagp;
    const int t = blockIdx.x * 256 + threadIdx.x;   // 0..32767
    const int lane = t & 63;
    const int kt = (t >> 6) & 15;
    const int c16 = t >> 10;
    const int src = (c16 * 16 + (lane & 15)) * 512 + kt * 32 + (lane >> 4) * 8;
    bf16x8 v1, v2;
    #pragma unroll
    for (int e = 0; e < 8; ++e) {
        v1[e] = (__bf16)ldsel(W1, src + e, isbf);
        v2[e] = (__bf16)ldsel(W2, src + e, isbf);
    }
    *reinterpret_cast<bf16x8*>(W1pk + (size_t)t * 8) = v1;
    *reinterpret_cast<bf16x8*>(W2pk + (size_t)t * 8) = v2;
}

// ---- prep: A -> bf16 fragment-major via LDS transpose (coalesced both sides).
// Apk chunk ((g*16 + kt)*64 + lane) = A[g*16 + (lane&15)][kt*32 + (lane>>4)*8 ..+8]
__global__ void aconv_kernel(const void* __restrict__ A, const int* __restrict__ flagp,
                             bf16_t* __restrict__ Apk) {
    __shared__ float As[16][516];   // pad 4 -> low bank aliasing on pack reads
    const int isbf = *flagp;
    const int t = threadIdx.x;      // 256
    const int g = blockIdx.x;       // 0..4095; rows g*16..+16
    if (isbf) {
        const bf16_t* Ab = (const bf16_t*)A + (size_t)g * 16 * 512;
        #pragma unroll
        for (int p = 0; p < 4; ++p) {
            const int c = p * 256 + t;          // 1024 chunks of 8 bf16
            const int row = c >> 6, col8 = c & 63;
            bf16x8 v = *reinterpret_cast<const bf16x8*>(Ab + row * 512 + col8 * 8);
            f32x4 f0, f1;
            f0.x = (float)v[0]; f0.y = (float)v[1]; f0.z = (float)v[2]; f0.w = (float)v[3];
            f1.x = (float)v[4]; f1.y = (float)v[5]; f1.z = (float)v[6]; f1.w = (float)v[7];
            *reinterpret_cast<f32x4*>(&As[row][col8 * 8])     = f0;
            *reinterpret_cast<f32x4*>(&As[row][col8 * 8 + 4]) = f1;
        }
    } else {
        const float* Af = (const float*)A + (size_t)g * 16 * 512;
        #pragma unroll
        for (int p = 0; p < 8; ++p) {
            const int c = p * 256 + t;          // 2048 chunks of 4 f32
            const int row = c >> 7, col4 = c & 127;
            f32x4 v = *reinterpret_cast<const f32x4*>(Af + row * 512 + col4 * 4);
            *reinterpret_cast<f32x4*>(&As[row][col4 * 4]) = v;
        }
    }
    __syncthreads();
    #pragma unroll
    for (int p = 0; p < 4; ++p) {
        const int c = p * 256 + t;              // 1024 chunks: kt x lane
        const int kt = c >> 6, lane = c & 63;
        const float* src = &As[lane & 15][kt * 32 + (lane >> 4) * 8];
        const f32x4 a0 = *reinterpret_cast<const f32x4*>(src);
        const f32x4 a1 = *reinterpret_cast<const f32x4*>(src + 4);
        bf16x8 v;
        v[0] = (__bf16)a0.x; v[1] = (__bf16)a0.y; v[2] = (__bf16)a0.z; v[3] = (__bf16)a0.w;
        v[4] = (__bf16)a1.x; v[5] = (__bf16)a1.y; v[6] = (__bf16)a1.z; v[7] = (__bf16)a1.w;
        *reinterpret_cast<bf16x8*>(Apk + ((size_t)(g * 16 + kt) * 64 + lane) * 8) = v;
    }
}

// ---- prep: wn_t[n][m] = w_norm[m][n] ----
__global__ void wnorm_kernel(const void* __restrict__ w, const int* __restrict__ flagp,
                             const float* __restrict__ dinv, float* __restrict__ wn_t) {
    const int isbf = *flagp;
    const int idx = blockIdx.x * 256 + threadIdx.x;   // 262144
    const int n = idx >> 9, m = idx & 511;
    float a = ldsel(w, n * 512 + m, isbf) + (m == n ? 1.0f : 0.0f);
    wn_t[idx] = a * dinv[m] * dinv[n];
}

// ---- fused MLP: 16 waves (2 row x 8 col groups), 64-row stripe, coalesced
//      global->reg operands, wave tile 32x64 (acc[4][2] = 32 AGPRs) ----
template <int PACKED>
__launch_bounds__(1024, 4)
__global__ void fused_mlp(const void* __restrict__ A,      // raw d (fallback path)
                          const bf16_t* __restrict__ Apk,  // fragment-major bf16
                          const bf16_t* __restrict__ W1pk,
                          const bf16_t* __restrict__ W2pk,
                          const float* __restrict__ sc1, const float* __restrict__ sh1,
                          const float* __restrict__ sc2, const float* __restrict__ sh2,
                          const float* __restrict__ wcf,   // 1024 f32
                          const int* __restrict__ flagp,
                          float* __restrict__ U)           // 65536 x 2
{
    __shared__ __align__(16) bf16_t T1s[BM * KDIM];   // 64 KB, XOR-swizzled rows
    __shared__ float Ured[8][BM][2];                  // 4 KB

    const int isbf = *flagp;
    const int tid = threadIdx.x;
    const int wave = tid >> 6, lane = tid & 63;
    const int wr = wave >> 3, wc = wave & 7;   // rows wr*32..+32, cols wc*64..+64
    const int bm = blockIdx.x;                 // 0..1023; rows bm*64..+64
    const int rl = lane & 15, hi = lane >> 4;

    // acc[j][i] = mfma(W_frag j, A_frag i): D row = out col, D col = A row
    f32x4 acc[4][2] = {};

    // ================= phase 1: T1 = lrelu(bn1(A @ W1^T)) =================
    for (int kt = 0; kt < 16; ++kt) {
        bf16x8 bfr[4], af[2];
        #pragma unroll
        for (int j = 0; j < 4; ++j)
            bfr[j] = *reinterpret_cast<const bf16x8*>(
                W1pk + ((size_t)((wc * 4 + j) * 16 + kt) * 64 + lane) * 8);
        #pragma unroll
        for (int i = 0; i < 2; ++i) {
            if (PACKED) {
                af[i] = *reinterpret_cast<const bf16x8*>(
                    Apk + ((size_t)((bm * 4 + wr * 2 + i) * 16 + kt) * 64 + lane) * 8);
            } else {
                const size_t arow = (size_t)(bm * BM + wr * 32 + i * 16 + rl) * KDIM
                                    + hi * 8 + kt * 32;
                if (isbf) {
                    af[i] = *reinterpret_cast<const bf16x8*>((const bf16_t*)A + arow);
                } else {
                    const f32x4* ap = (const f32x4*)((const float*)A + arow);
                    const f32x4 a0 = ap[0], a1 = ap[1];
                    bf16x8 v;
                    v[0] = (__bf16)a0.x; v[1] = (__bf16)a0.y; v[2] = (__bf16)a0.z; v[3] = (__bf16)a0.w;
                    v[4] = (__bf16)a1.x; v[5] = (__bf16)a1.y; v[6] = (__bf16)a1.z; v[7] = (__bf16)a1.w;
                    af[i] = v;
                }
            }
        }
        #pragma unroll
        for (int j = 0; j < 4; ++j)
            #pragma unroll
            for (int i = 0; i < 2; ++i)
                acc[j][i] = __builtin_amdgcn_mfma_f32_16x16x32_bf16(bfr[j], af[i], acc[j][i], 0, 0, 0);
    }

    // epilogue 1: BN + LReLU; lane holds 4 ADJACENT out-cols -> b64 store
    #pragma unroll
    for (int j = 0; j < 4; ++j) {
        const int gcol0 = wc * 64 + j * 16 + hi * 4;
        const f32x4 s4 = *reinterpret_cast<const f32x4*>(&sc1[gcol0]);
        const f32x4 h4 = *reinterpret_cast<const f32x4*>(&sh1[gcol0]);
        #pragma unroll
        for (int i = 0; i < 2; ++i) {
            const int row = wr * 32 + i * 16 + rl;
            int off = (row << 10) + (gcol0 << 1);
            off ^= (row & 7) << 4;
            bf16x4 pk;
            #pragma unroll
            for (int r = 0; r < 4; ++r) {
                float y = acc[j][i][r] * s4[r] + h4[r];
                y = y > 0.f ? y : 0.1f * y;
                pk[r] = (__bf16)y;
            }
            *reinterpret_cast<bf16x4*>((char*)T1s + off) = pk;
        }
    }
    __syncthreads();

    // ================= phase 2: Y2 = lrelu(bn2(T1 @ W2^T)); U = Y2 @ Wc^T =================
    #pragma unroll
    for (int j = 0; j < 4; ++j)
        #pragma unroll
        for (int i = 0; i < 2; ++i)
            acc[j][i] = f32x4{0.f, 0.f, 0.f, 0.f};

    for (int kt = 0; kt < 16; ++kt) {
        bf16x8 bfr[4], af[2];
        #pragma unroll
        for (int j = 0; j < 4; ++j)
            bfr[j] = *reinterpret_cast<const bf16x8*>(
                W2pk + ((size_t)((wc * 4 + j) * 16 + kt) * 64 + lane) * 8);
        #pragma unroll
        for (int i = 0; i < 2; ++i) {
            const int row = wr * 32 + i * 16 + rl;
            int off = (row << 10) + kt * 64 + hi * 16;
            off ^= (row & 7) << 4;
            af[i] = *reinterpret_cast<const bf16x8*>((const char*)T1s + off);
        }
        #pragma unroll
        for (int j = 0; j < 4; ++j)
            #pragma unroll
            for (int i = 0; i < 2; ++i)
                acc[j][i] = __builtin_amdgcn_mfma_f32_16x16x32_bf16(bfr[j], af[i], acc[j][i], 0, 0, 0);
    }

    // epilogue 2: BN + LReLU + 512->2 projection (in-lane over j,r; shfl over hi)
    float p0[2] = {0.f, 0.f}, p1[2] = {0.f, 0.f};
    #pragma unroll
    for (int j = 0; j < 4; ++j) {
        const int gcol0 = wc * 64 + j * 16 + hi * 4;
        const f32x4 s4 = *reinterpret_cast<const f32x4*>(&sc2[gcol0]);
        const f32x4 h4 = *reinterpret_cast<const f32x4*>(&sh2[gcol0]);
        const f32x4 w0 = *reinterpret_cast<const f32x4*>(&wcf[gcol0]);
        const f32x4 w1 = *reinterpret_cast<const f32x4*>(&wcf[512 + gcol0]);
        #pragma unroll
        for (int i = 0; i < 2; ++i)
            #pragma unroll
            for (int r = 0; r < 4; ++r) {
                float y = acc[j][i][r] * s4[r] + h4[r];
                y = y > 0.f ? y : 0.1f * y;
                p0[i] += y * w0[r];
                p1[i] += y * w1[r];
            }
    }
    #pragma unroll
    for (int i = 0; i < 2; ++i) {
        float a = p0[i], b = p1[i];
        a += __shfl_xor(a, 16, 64);  b += __shfl_xor(b, 16, 64);
        a += __shfl_xor(a, 32, 64);  b += __shfl_xor(b, 32, 64);
        if (hi == 0) {
            const int row = wr * 32 + i * 16 + rl;
            Ured[wc][row][0] = a;
            Ured[wc][row][1] = b;
        }
    }
    __syncthreads();
    if (tid < BM * 2) {
        const int row = tid >> 1, c = tid & 1;
        float s = 0.f;
        #pragma unroll
        for (int q = 0; q < 8; ++q) s += Ured[q][row][c];
        U[(size_t)(bm * BM + row) * 2 + c] = s;
    }
}

// ---- GCN on 2-wide features ----
__global__ void gcn_kernel(const float* __restrict__ wn_t, const float* __restrict__ U,
                           const float* __restrict__ bcf, const int* __restrict__ flagp,
                           void* __restrict__ out) {
    const int isbf = *flagp;
    const int wave = threadIdx.x >> 6, lane = threadIdx.x & 63;
    const int task = blockIdx.x * 4 + wave;   // (b, n)
    const int b = task >> 9, n = task & 511;
    const float* wrow = wn_t + n * 512;
    const float* ub = U + b * 1024;
    float a0 = 0.f, a1 = 0.f;
    for (int m = lane; m < 512; m += 64) {
        const float wv = wrow[m];
        a0 += wv * ub[m * 2];
        a1 += wv * ub[m * 2 + 1];
    }
    #pragma unroll
    for (int off = 32; off; off >>= 1) {
        a0 += __shfl_down(a0, off, 64);
        a1 += __shfl_down(a1, off, 64);
    }
    if (lane == 0) {
        const float r0 = a0 + bcf[0];
        const float r1 = a1 + bcf[1];
        if (isbf) {
            ((bf16_t*)out)[task * 2]     = __float2bfloat16(r0);
            ((bf16_t*)out)[task * 2 + 1] = __float2bfloat16(r1);
        } else {
            ((float*)out)[task * 2]     = r0;
            ((float*)out)[task * 2 + 1] = r1;
        }
    }
}

extern "C" void kernel_launch(void* const* d_in, const int* in_sizes, int n_in,
                              void* d_out, int out_size, void* d_ws, size_t ws_size,
                              hipStream_t stream) {
    const void* d   = d_in[0];
    const void* w   = d_in[1];
    const void* W1  = d_in[2];
    const void* b1  = d_in[3];
    const void* g1  = d_in[4];
    const void* be1 = d_in[5];
    const void* m1  = d_in[6];
    const void* v1  = d_in[7];
    const void* W2  = d_in[8];
    const void* b2  = d_in[9];
    const void* g2  = d_in[10];
    const void* be2 = d_in[11];
    const void* m2  = d_in[12];
    const void* v2  = d_in[13];
    const void* Wc  = d_in[14];
    const void* bc  = d_in[15];

    // workspace layout: 3 MB small buffers + 64 MB Apk
    char* ws = (char*)d_ws;
    float*  wn_t = (float*)ws;                         // 1 MB
    bf16_t* W1pk = (bf16_t*)(ws + 0x100000);           // 512 KB (fragment-major)
    bf16_t* W2pk = (bf16_t*)(ws + 0x180000);           // 512 KB
    float*  sc1  = (float*)(ws + 0x200000);
    float*  sh1  = sc1 + 512;
    float*  sc2  = sh1 + 512;
    float*  sh2  = sc2 + 512;
    float*  dinv = sh2 + 512;
    float*  wcf  = (float*)(ws + 0x204000);            // 4 KB
    float*  bcf  = (float*)(ws + 0x205000);
    int*    flag = (int*)(ws + 0x205100);
    float*  U    = (float*)(ws + 0x208000);            // 512 KB
    bf16_t* Apk  = (bf16_t*)(ws + 0x300000);           // 64 MB (fragment-major A)

    const size_t NEED = 0x300000 + (size_t)65536 * 512 * sizeof(bf16_t);
    const bool packed = ws_size >= NEED;

    const int M = 128 * 512;   // 65536 rows

    probe_kernel<<<1, 64, 0, stream>>>(d, flag);
    rowsum_kernel<<<512, 64, 0, stream>>>(w, flag, dinv);
    params_kernel<<<1, 512, 0, stream>>>(g1, b1, m1, v1, be1, g2, b2, m2, v2, be2,
                                         Wc, bc, flag, sc1, sh1, sc2, sh2, wcf, bcf);
    wconv_kernel<<<128, 256, 0, stream>>>(W1, W2, flag, W1pk, W2pk);
    wnorm_kernel<<<1024, 256, 0, stream>>>(w, flag, dinv, wn_t);

    if (packed) {
        aconv_kernel<<<M / 16, 256, 0, stream>>>(d, flag, Apk);
        fused_mlp<1><<<M / BM, 1024, 0, stream>>>(d, Apk, W1pk, W2pk,
                                                  sc1, sh1, sc2, sh2, wcf, flag, U);
    } else {
        fused_mlp<0><<<M / BM, 1024, 0, stream>>>(d, Apk, W1pk, W2pk,
                                                  sc1, sh1, sc2, sh2, wcf, flag, U);
    }

    gcn_kernel<<<M / 4, 256, 0, stream>>>(wn_t, U, bcf, flag, d_out);
}

// Round 9
// 182.780 us; speedup vs baseline: 2.0159x; 1.1809x over previous
//
#include <hip/hip_runtime.h>
#include <hip/hip_bf16.h>

// Sggnn_gcn — fused 2x(Linear512+BN+LReLU) + Wc projection, then GCN on 2-wide
// features. Restructuring: (w_norm^T @ t) @ Wc^T == w_norm^T @ (t @ Wc^T).
// v9: v8 (fragment-major packed coalesced operands, 16-wave blocks, BM=64,
// acc[4][2]) + DEPTH-1 REGISTER PREFETCH: kt-loop unrolled x2 with two named
// operand sets, so the 6 global loads of kt+1 are in flight while kt's MFMAs
// run (v8 was latency-bound: 4 waves/SIMD x 44cyc issue vs ~450cyc L2 latency
// = the measured 19.5% MfmaUtil). Ured unioned into T1s -> LDS exactly 64 KB.

typedef __hip_bfloat16 bf16_t;
typedef __bf16 bf16x8 __attribute__((ext_vector_type(8)));
typedef __bf16 bf16x4 __attribute__((ext_vector_type(4)));
typedef float f32x4 __attribute__((ext_vector_type(4)));

#define KDIM 512
#define BM 64      // rows per block

// load element i of a logically-f32 vector that may be stored as bf16
__device__ __forceinline__ float ldsel(const void* p, int i, int isbf) {
    return isbf ? __bfloat162float(((const bf16_t*)p)[i]) : ((const float*)p)[i];
}

// ---- probe: detect dtype of d (bf16 vs f32) from exponent statistics ----
__global__ void probe_kernel(const void* __restrict__ d, int* __restrict__ flag) {
    const unsigned short* u = (const unsigned short*)d;
    const int l = threadIdx.x;   // 64
    int cnt = 0;
    for (int i = l; i < 256; i += 64) {
        const int e = (u[i] >> 7) & 0xFF;
        cnt += (e >= 118 && e <= 129) ? 1 : 0;
    }
    #pragma unroll
    for (int off = 32; off; off >>= 1) cnt += __shfl_down(cnt, off, 64);
    if (l == 0) *flag = (cnt >= 200) ? 1 : 0;   // bf16 ~255, f32 ~134
}

// ---- prep: rowsum of adj = w + I  ->  d_inv_sqrt ----
__global__ void rowsum_kernel(const void* __restrict__ w, const int* __restrict__ flagp,
                              float* __restrict__ dinv) {
    const int isbf = *flagp;
    const int i = blockIdx.x;
    const int l = threadIdx.x;
    float s = 0.f;
    for (int j = l; j < 512; j += 64) s += ldsel(w, i * 512 + j, isbf);
    #pragma unroll
    for (int off = 32; off; off >>= 1) s += __shfl_down(s, off, 64);
    if (l == 0) dinv[i] = 1.0f / sqrtf(s + 1.0f);
}

// ---- prep: fold BN -> scale/shift; canonicalize Wc, bc to f32 ----
__global__ void params_kernel(const void* g1, const void* b1, const void* m1,
                              const void* v1, const void* be1,
                              const void* g2, const void* b2, const void* m2,
                              const void* v2, const void* be2,
                              const void* Wc, const void* bc,
                              const int* __restrict__ flagp,
                              float* sc1, float* sh1, float* sc2, float* sh2,
                              float* wcf, float* bcf) {
    const int isbf = *flagp;
    const int i = threadIdx.x;  // 512
    float s1 = ldsel(g1, i, isbf) / sqrtf(ldsel(v1, i, isbf) + 1e-5f);
    sc1[i] = s1;
    sh1[i] = (ldsel(b1, i, isbf) - ldsel(m1, i, isbf)) * s1 + ldsel(be1, i, isbf);
    float s2 = ldsel(g2, i, isbf) / sqrtf(ldsel(v2, i, isbf) + 1e-5f);
    sc2[i] = s2;
    sh2[i] = (ldsel(b2, i, isbf) - ldsel(m2, i, isbf)) * s2 + ldsel(be2, i, isbf);
    wcf[i] = ldsel(Wc, i, isbf);
    wcf[512 + i] = ldsel(Wc, 512 + i, isbf);
    if (i < 2) bcf[i] = ldsel(bc, i, isbf);
}

// ---- prep: W1,W2 -> bf16 in FRAGMENT-MAJOR order.
// chunk t = ((c16*16 + kt)*64 + lane); data = W[c16*16 + (lane&15)][kt*32 + (lane>>4)*8 ..+8]
__global__ void wconv_kernel(const void* __restrict__ W1, const void* __restrict__ W2,
                             const int* __restrict__ flagp,
                             bf16_t* __restrict__ W1pk, bf16_t* __restrict__ W2pk) {
    const int isbf = *flagp;
    const int t = blockIdx.x * 256 + threadIdx.x;   // 0..32767
    const int lane = t & 63;
    const int kt = (t >> 6) & 15;
    const int c16 = t >> 10;
    const int src = (c16 * 16 + (lane & 15)) * 512 + kt * 32 + (lane >> 4) * 8;
    bf16x8 v1, v2;
    #pragma unroll
    for (int e = 0; e < 8; ++e) {
        v1[e] = (__bf16)ldsel(W1, src + e, isbf);
        v2[e] = (__bf16)ldsel(W2, src + e, isbf);
    }
    *reinterpret_cast<bf16x8*>(W1pk + (size_t)t * 8) = v1;
    *reinterpret_cast<bf16x8*>(W2pk + (size_t)t * 8) = v2;
}

// ---- prep: A -> bf16 fragment-major via LDS transpose (coalesced both sides).
// Apk chunk ((g*16 + kt)*64 + lane) = A[g*16 + (lane&15)][kt*32 + (lane>>4)*8 ..+8]
__global__ void aconv_kernel(const void* __restrict__ A, const int* __restrict__ flagp,
                             bf16_t* __restrict__ Apk) {
    __shared__ float As[16][516];   // pad 4 -> low bank aliasing on pack reads
    const int isbf = *flagp;
    const int t = threadIdx.x;      // 256
    const int g = blockIdx.x;       // 0..4095; rows g*16..+16
    if (isbf) {
        const bf16_t* Ab = (const bf16_t*)A + (size_t)g * 16 * 512;
        #pragma unroll
        for (int p = 0; p < 4; ++p) {
            const int c = p * 256 + t;          // 1024 chunks of 8 bf16
            const int row = c >> 6, col8 = c & 63;
            bf16x8 v = *reinterpret_cast<const bf16x8*>(Ab + row * 512 + col8 * 8);
            f32x4 f0, f1;
            f0.x = (float)v[0]; f0.y = (float)v[1]; f0.z = (float)v[2]; f0.w = (float)v[3];
            f1.x = (float)v[4]; f1.y = (float)v[5]; f1.z = (float)v[6]; f1.w = (float)v[7];
            *reinterpret_cast<f32x4*>(&As[row][col8 * 8])     = f0;
            *reinterpret_cast<f32x4*>(&As[row][col8 * 8 + 4]) = f1;
        }
    } else {
        const float* Af = (const float*)A + (size_t)g * 16 * 512;
        #pragma unroll
        for (int p = 0; p < 8; ++p) {
            const int c = p * 256 + t;          // 2048 chunks of 4 f32
            const int row = c >> 7, col4 = c & 127;
            f32x4 v = *reinterpret_cast<const f32x4*>(Af + row * 512 + col4 * 4);
            *reinterpret_cast<f32x4*>(&As[row][col4 * 4]) = v;
        }
    }
    __syncthreads();
    #pragma unroll
    for (int p = 0; p < 4; ++p) {
        const int c = p * 256 + t;              // 1024 chunks: kt x lane
        const int kt = c >> 6, lane = c & 63;
        const float* src = &As[lane & 15][kt * 32 + (lane >> 4) * 8];
        const f32x4 a0 = *reinterpret_cast<const f32x4*>(src);
        const f32x4 a1 = *reinterpret_cast<const f32x4*>(src + 4);
        bf16x8 v;
        v[0] = (__bf16)a0.x; v[1] = (__bf16)a0.y; v[2] = (__bf16)a0.z; v[3] = (__bf16)a0.w;
        v[4] = (__bf16)a1.x; v[5] = (__bf16)a1.y; v[6] = (__bf16)a1.z; v[7] = (__bf16)a1.w;
        *reinterpret_cast<bf16x8*>(Apk + ((size_t)(g * 16 + kt) * 64 + lane) * 8) = v;
    }
}

// ---- prep: wn_t[n][m] = w_norm[m][n] ----
__global__ void wnorm_kernel(const void* __restrict__ w, const int* __restrict__ flagp,
                             const float* __restrict__ dinv, float* __restrict__ wn_t) {
    const int isbf = *flagp;
    const int idx = blockIdx.x * 256 + threadIdx.x;   // 262144
    const int n = idx >> 9, m = idx & 511;
    float a = ldsel(w, n * 512 + m, isbf) + (m == n ? 1.0f : 0.0f);
    wn_t[idx] = a * dinv[m] * dinv[n];
}

// fragment-major strides (bytes): j/i-group stride 16 KB, kt stride 1 KB
#define JSTRIDE 16384
#define KSTRIDE 1024

#define LOADW(dst, base, kt)                                                   \
    _Pragma("unroll")                                                          \
    for (int j = 0; j < 4; ++j)                                                \
        dst[j] = *reinterpret_cast<const bf16x8*>((base) + j * JSTRIDE + (kt) * KSTRIDE);

#define LOADA(dst, base, kt)                                                   \
    _Pragma("unroll")                                                          \
    for (int i = 0; i < 2; ++i)                                                \
        dst[i] = *reinterpret_cast<const bf16x8*>((base) + i * JSTRIDE + (kt) * KSTRIDE);

#define MFMA8(bset, aset)                                                      \
    _Pragma("unroll")                                                          \
    for (int j = 0; j < 4; ++j)                                                \
        _Pragma("unroll")                                                      \
        for (int i = 0; i < 2; ++i)                                            \
            acc[j][i] = __builtin_amdgcn_mfma_f32_16x16x32_bf16(bset[j], aset[i], acc[j][i], 0, 0, 0);

// ---- fused MLP: 16 waves (2 row x 8 col groups), BM=64, coalesced packed
//      operands, depth-1 register prefetch ----
template <int PACKED>
__launch_bounds__(1024, 4)
__global__ void fused_mlp(const void* __restrict__ A,      // raw d (fallback path)
                          const bf16_t* __restrict__ Apk,  // fragment-major bf16
                          const bf16_t* __restrict__ W1pk,
                          const bf16_t* __restrict__ W2pk,
                          const float* __restrict__ sc1, const float* __restrict__ sh1,
                          const float* __restrict__ sc2, const float* __restrict__ sh2,
                          const float* __restrict__ wcf,   // 1024 f32
                          const int* __restrict__ flagp,
                          float* __restrict__ U)           // 65536 x 2
{
    __shared__ __align__(16) bf16_t T1s[BM * KDIM];   // 64 KB; Ured unioned in
    float* UredF = (float*)T1s;                       // [8][64][2] after phase 2

    const int isbf = *flagp;
    const int tid = threadIdx.x;
    const int wave = tid >> 6, lane = tid & 63;
    const int wr = wave >> 3, wc = wave & 7;   // rows wr*32..+32, cols wc*64..+64
    const int bm = blockIdx.x;                 // 0..1023; rows bm*64..+64
    const int rl = lane & 15, hi = lane >> 4;

    // per-lane fragment-major base pointers
    const char* w1base = (const char*)W1pk + ((size_t)(wc * 4) * 16 * 64 + lane) * 16;
    const char* w2base = (const char*)W2pk + ((size_t)(wc * 4) * 16 * 64 + lane) * 16;
    const char* abase  = (const char*)Apk + ((size_t)(bm * 4 + wr * 2) * 16 * 64 + lane) * 16;

    // acc[j][i] = mfma(W_frag j, A_frag i): D row = out col, D col = A row
    f32x4 acc[4][2] = {};
    bf16x8 bA[4], aA[2], bB[4], aB[2];

    // ================= phase 1: T1 = lrelu(bn1(A @ W1^T)) =================
    if (PACKED) {
        LOADW(bA, w1base, 0);
        LOADA(aA, abase, 0);
        #pragma unroll 2
        for (int kt = 0; kt < 16; kt += 2) {
            if (kt + 1 < 16) { LOADW(bB, w1base, kt + 1); LOADA(aB, abase, kt + 1); }
            MFMA8(bA, aA);
            if (kt + 2 < 16) { LOADW(bA, w1base, kt + 2); LOADA(aA, abase, kt + 2); }
            MFMA8(bB, aB);
        }
    } else {
        for (int kt = 0; kt < 16; ++kt) {
            LOADW(bA, w1base, kt);
            #pragma unroll
            for (int i = 0; i < 2; ++i) {
                const size_t arow = (size_t)(bm * BM + wr * 32 + i * 16 + rl) * KDIM
                                    + hi * 8 + kt * 32;
                if (isbf) {
                    aA[i] = *reinterpret_cast<const bf16x8*>((const bf16_t*)A + arow);
                } else {
                    const f32x4* ap = (const f32x4*)((const float*)A + arow);
                    const f32x4 a0 = ap[0], a1 = ap[1];
                    bf16x8 v;
                    v[0] = (__bf16)a0.x; v[1] = (__bf16)a0.y; v[2] = (__bf16)a0.z; v[3] = (__bf16)a0.w;
                    v[4] = (__bf16)a1.x; v[5] = (__bf16)a1.y; v[6] = (__bf16)a1.z; v[7] = (__bf16)a1.w;
                    aA[i] = v;
                }
            }
            MFMA8(bA, aA);
        }
    }

    // epilogue 1: BN + LReLU; lane holds 4 ADJACENT out-cols -> b64 store
    #pragma unroll
    for (int j = 0; j < 4; ++j) {
        const int gcol0 = wc * 64 + j * 16 + hi * 4;
        const f32x4 s4 = *reinterpret_cast<const f32x4*>(&sc1[gcol0]);
        const f32x4 h4 = *reinterpret_cast<const f32x4*>(&sh1[gcol0]);
        #pragma unroll
        for (int i = 0; i < 2; ++i) {
            const int row = wr * 32 + i * 16 + rl;
            int off = (row << 10) + (gcol0 << 1);
            off ^= (row & 7) << 4;
            bf16x4 pk;
            #pragma unroll
            for (int r = 0; r < 4; ++r) {
                float y = acc[j][i][r] * s4[r] + h4[r];
                y = y > 0.f ? y : 0.1f * y;
                pk[r] = (__bf16)y;
            }
            *reinterpret_cast<bf16x4*>((char*)T1s + off) = pk;
        }
    }
    __syncthreads();

    // ================= phase 2: Y2 = lrelu(bn2(T1 @ W2^T)); U = Y2 @ Wc^T =================
    #pragma unroll
    for (int j = 0; j < 4; ++j)
        #pragma unroll
        for (int i = 0; i < 2; ++i)
            acc[j][i] = f32x4{0.f, 0.f, 0.f, 0.f};

    // T1s fragment read for k-tile kt (XOR-swizzled rows)
    #define LDT1(dst, kt)                                                      \
        _Pragma("unroll")                                                      \
        for (int i = 0; i < 2; ++i) {                                          \
            const int row_ = wr * 32 + i * 16 + rl;                            \
            int off_ = (row_ << 10) + (kt) * 64 + hi * 16;                     \
            off_ ^= (row_ & 7) << 4;                                           \
            dst[i] = *reinterpret_cast<const bf16x8*>((const char*)T1s + off_);\
        }

    LOADW(bA, w2base, 0);
    #pragma unroll 2
    for (int kt = 0; kt < 16; kt += 2) {
        if (kt + 1 < 16) LOADW(bB, w2base, kt + 1);
        LDT1(aA, kt);
        MFMA8(bA, aA);
        if (kt + 2 < 16) LOADW(bA, w2base, kt + 2);
        LDT1(aB, kt + 1);
        MFMA8(bB, aB);
    }

    // epilogue 2: BN + LReLU + 512->2 projection (in-lane over j,r; shfl over hi)
    float p0[2] = {0.f, 0.f}, p1[2] = {0.f, 0.f};
    #pragma unroll
    for (int j = 0; j < 4; ++j) {
        const int gcol0 = wc * 64 + j * 16 + hi * 4;
        const f32x4 s4 = *reinterpret_cast<const f32x4*>(&sc2[gcol0]);
        const f32x4 h4 = *reinterpret_cast<const f32x4*>(&sh2[gcol0]);
        const f32x4 w0 = *reinterpret_cast<const f32x4*>(&wcf[gcol0]);
        const f32x4 w1 = *reinterpret_cast<const f32x4*>(&wcf[512 + gcol0]);
        #pragma unroll
        for (int i = 0; i < 2; ++i)
            #pragma unroll
            for (int r = 0; r < 4; ++r) {
                float y = acc[j][i][r] * s4[r] + h4[r];
                y = y > 0.f ? y : 0.1f * y;
                p0[i] += y * w0[r];
                p1[i] += y * w1[r];
            }
    }
    __syncthreads();   // all T1s reads done before Ured overlays the space
    #pragma unroll
    for (int i = 0; i < 2; ++i) {
        float a = p0[i], b = p1[i];
        a += __shfl_xor(a, 16, 64);  b += __shfl_xor(b, 16, 64);
        a += __shfl_xor(a, 32, 64);  b += __shfl_xor(b, 32, 64);
        if (hi == 0) {
            const int row = wr * 32 + i * 16 + rl;
            UredF[(wc * BM + row) * 2]     = a;
            UredF[(wc * BM + row) * 2 + 1] = b;
        }
    }
    __syncthreads();
    if (tid < BM * 2) {
        const int row = tid >> 1, c = tid & 1;
        float s = 0.f;
        #pragma unroll
        for (int q = 0; q < 8; ++q) s += UredF[(q * BM + row) * 2 + c];
        U[(size_t)(bm * BM + row) * 2 + c] = s;
    }
    #undef LDT1
}

// ---- GCN on 2-wide features ----
__global__ void gcn_kernel(const float* __restrict__ wn_t, const float* __restrict__ U,
                           const float* __restrict__ bcf, const int* __restrict__ flagp,
                           void* __restrict__ out) {
    const int isbf = *flagp;
    const int wave = threadIdx.x >> 6, lane = threadIdx.x & 63;
    const int task = blockIdx.x * 4 + wave;   // (b, n)
    const int b = task >> 9, n = task & 511;
    const float* wrow = wn_t + n * 512;
    const float* ub = U + b * 1024;
    float a0 = 0.f, a1 = 0.f;
    for (int m = lane; m < 512; m += 64) {
        const float wv = wrow[m];
        a0 += wv * ub[m * 2];
        a1 += wv * ub[m * 2 + 1];
    }
    #pragma unroll
    for (int off = 32; off; off >>= 1) {
        a0 += __shfl_down(a0, off, 64);
        a1 += __shfl_down(a1, off, 64);
    }
    if (lane == 0) {
        const float r0 = a0 + bcf[0];
        const float r1 = a1 + bcf[1];
        if (isbf) {
            ((bf16_t*)out)[task * 2]     = __float2bfloat16(r0);
            ((bf16_t*)out)[task * 2 + 1] = __float2bfloat16(r1);
        } else {
            ((float*)out)[task * 2]     = r0;
            ((float*)out)[task * 2 + 1] = r1;
        }
    }
}

extern "C" void kernel_launch(void* const* d_in, const int* in_sizes, int n_in,
                              void* d_out, int out_size, void* d_ws, size_t ws_size,
                              hipStream_t stream) {
    const void* d   = d_in[0];
    const void* w   = d_in[1];
    const void* W1  = d_in[2];
    const void* b1  = d_in[3];
    const void* g1  = d_in[4];
    const void* be1 = d_in[5];
    const void* m1  = d_in[6];
    const void* v1  = d_in[7];
    const void* W2  = d_in[8];
    const void* b2  = d_in[9];
    const void* g2  = d_in[10];
    const void* be2 = d_in[11];
    const void* m2  = d_in[12];
    const void* v2  = d_in[13];
    const void* Wc  = d_in[14];
    const void* bc  = d_in[15];

    // workspace layout: 3 MB small buffers + 64 MB Apk
    char* ws = (char*)d_ws;
    float*  wn_t = (float*)ws;                         // 1 MB
    bf16_t* W1pk = (bf16_t*)(ws + 0x100000);           // 512 KB (fragment-major)
    bf16_t* W2pk = (bf16_t*)(ws + 0x180000);           // 512 KB
    float*  sc1  = (float*)(ws + 0x200000);
    float*  sh1  = sc1 + 512;
    float*  sc2  = sh1 + 512;
    float*  sh2  = sc2 + 512;
    float*  dinv = sh2 + 512;
    float*  wcf  = (float*)(ws + 0x204000);            // 4 KB
    float*  bcf  = (float*)(ws + 0x205000);
    int*    flag = (int*)(ws + 0x205100);
    float*  U    = (float*)(ws + 0x208000);            // 512 KB
    bf16_t* Apk  = (bf16_t*)(ws + 0x300000);           // 64 MB (fragment-major A)

    const size_t NEED = 0x300000 + (size_t)65536 * 512 * sizeof(bf16_t);
    const bool packed = ws_size >= NEED;

    const int M = 128 * 512;   // 65536 rows

    probe_kernel<<<1, 64, 0, stream>>>(d, flag);
    rowsum_kernel<<<512, 64, 0, stream>>>(w, flag, dinv);
    params_kernel<<<1, 512, 0, stream>>>(g1, b1, m1, v1, be1, g2, b2, m2, v2, be2,
                                         Wc, bc, flag, sc1, sh1, sc2, sh2, wcf, bcf);
    wconv_kernel<<<128, 256, 0, stream>>>(W1, W2, flag, W1pk, W2pk);
    wnorm_kernel<<<1024, 256, 0, stream>>>(w, flag, dinv, wn_t);

    if (packed) {
        aconv_kernel<<<M / 16, 256, 0, stream>>>(d, flag, Apk);
        fused_mlp<1><<<M / BM, 1024, 0, stream>>>(d, Apk, W1pk, W2pk,
                                                  sc1, sh1, sc2, sh2, wcf, flag, U);
    } else {
        fused_mlp<0><<<M / BM, 1024, 0, stream>>>(d, Apk, W1pk, W2pk,
                                                  sc1, sh1, sc2, sh2, wcf, flag, U);
    }

    gcn_kernel<<<M / 4, 256, 0, stream>>>(wn_t, U, bcf, flag, d_out);
}

// Round 10
// 165.443 us; speedup vs baseline: 2.2272x; 1.1048x over previous
//
#include <hip/hip_runtime.h>
#include <hip/hip_bf16.h>

// Sggnn_gcn — fused 2x(Linear512+BN+LReLU) + Wc projection, then GCN on 2-wide
// features. Restructuring: (w_norm^T @ t) @ Wc^T == w_norm^T @ (t @ Wc^T).
// v10: BM=128 with W-register reuse across two 32-row halves (accA/accB).
// Per kt: 4 W-loads + 4 A-loads -> 16 MFMA (2.0 ratio vs v9's 1.33); W L2
// traffic halves to 1 GB (512 blocks x 2 MB). Regs ~120 <= 128 cap (4 w/SIMD).
// T1s = 128 KB LDS (+8 KB Ured).

typedef __hip_bfloat16 bf16_t;
typedef __bf16 bf16x8 __attribute__((ext_vector_type(8)));
typedef __bf16 bf16x4 __attribute__((ext_vector_type(4)));
typedef float f32x4 __attribute__((ext_vector_type(4)));

#define KDIM 512
#define BM 128     // rows per block

// load element i of a logically-f32 vector that may be stored as bf16
__device__ __forceinline__ float ldsel(const void* p, int i, int isbf) {
    return isbf ? __bfloat162float(((const bf16_t*)p)[i]) : ((const float*)p)[i];
}

// ---- probe: detect dtype of d (bf16 vs f32) from exponent statistics ----
__global__ void probe_kernel(const void* __restrict__ d, int* __restrict__ flag) {
    const unsigned short* u = (const unsigned short*)d;
    const int l = threadIdx.x;   // 64
    int cnt = 0;
    for (int i = l; i < 256; i += 64) {
        const int e = (u[i] >> 7) & 0xFF;
        cnt += (e >= 118 && e <= 129) ? 1 : 0;
    }
    #pragma unroll
    for (int off = 32; off; off >>= 1) cnt += __shfl_down(cnt, off, 64);
    if (l == 0) *flag = (cnt >= 200) ? 1 : 0;   // bf16 ~255, f32 ~134
}

// ---- prep: rowsum of adj = w + I  ->  d_inv_sqrt ----
__global__ void rowsum_kernel(const void* __restrict__ w, const int* __restrict__ flagp,
                              float* __restrict__ dinv) {
    const int isbf = *flagp;
    const int i = blockIdx.x;
    const int l = threadIdx.x;
    float s = 0.f;
    for (int j = l; j < 512; j += 64) s += ldsel(w, i * 512 + j, isbf);
    #pragma unroll
    for (int off = 32; off; off >>= 1) s += __shfl_down(s, off, 64);
    if (l == 0) dinv[i] = 1.0f / sqrtf(s + 1.0f);
}

// ---- prep: fold BN -> scale/shift; canonicalize Wc, bc to f32 ----
__global__ void params_kernel(const void* g1, const void* b1, const void* m1,
                              const void* v1, const void* be1,
                              const void* g2, const void* b2, const void* m2,
                              const void* v2, const void* be2,
                              const void* Wc, const void* bc,
                              const int* __restrict__ flagp,
                              float* sc1, float* sh1, float* sc2, float* sh2,
                              float* wcf, float* bcf) {
    const int isbf = *flagp;
    const int i = threadIdx.x;  // 512
    float s1 = ldsel(g1, i, isbf) / sqrtf(ldsel(v1, i, isbf) + 1e-5f);
    sc1[i] = s1;
    sh1[i] = (ldsel(b1, i, isbf) - ldsel(m1, i, isbf)) * s1 + ldsel(be1, i, isbf);
    float s2 = ldsel(g2, i, isbf) / sqrtf(ldsel(v2, i, isbf) + 1e-5f);
    sc2[i] = s2;
    sh2[i] = (ldsel(b2, i, isbf) - ldsel(m2, i, isbf)) * s2 + ldsel(be2, i, isbf);
    wcf[i] = ldsel(Wc, i, isbf);
    wcf[512 + i] = ldsel(Wc, 512 + i, isbf);
    if (i < 2) bcf[i] = ldsel(bc, i, isbf);
}

// ---- prep: W1,W2 -> bf16 in FRAGMENT-MAJOR order.
// chunk t = ((c16*16 + kt)*64 + lane); data = W[c16*16 + (lane&15)][kt*32 + (lane>>4)*8 ..+8]
__global__ void wconv_kernel(const void* __restrict__ W1, const void* __restrict__ W2,
                             const int* __restrict__ flagp,
                             bf16_t* __restrict__ W1pk, bf16_t* __restrict__ W2pk) {
    const int isbf = *flagp;
    const int t = blockIdx.x * 256 + threadIdx.x;   // 0..32767
    const int lane = t & 63;
    const int kt = (t >> 6) & 15;
    const int c16 = t >> 10;
    const int src = (c16 * 16 + (lane & 15)) * 512 + kt * 32 + (lane >> 4) * 8;
    bf16x8 v1, v2;
    #pragma unroll
    for (int e = 0; e < 8; ++e) {
        v1[e] = (__bf16)ldsel(W1, src + e, isbf);
        v2[e] = (__bf16)ldsel(W2, src + e, isbf);
    }
    *reinterpret_cast<bf16x8*>(W1pk + (size_t)t * 8) = v1;
    *reinterpret_cast<bf16x8*>(W2pk + (size_t)t * 8) = v2;
}

// ---- prep: A -> bf16 fragment-major via LDS transpose (coalesced both sides).
// Apk chunk ((g*16 + kt)*64 + lane) = A[g*16 + (lane&15)][kt*32 + (lane>>4)*8 ..+8]
__global__ void aconv_kernel(const void* __restrict__ A, const int* __restrict__ flagp,
                             bf16_t* __restrict__ Apk) {
    __shared__ float As[16][516];   // pad 4 -> low bank aliasing on pack reads
    const int isbf = *flagp;
    const int t = threadIdx.x;      // 256
    const int g = blockIdx.x;       // 0..4095; rows g*16..+16
    if (isbf) {
        const bf16_t* Ab = (const bf16_t*)A + (size_t)g * 16 * 512;
        #pragma unroll
        for (int p = 0; p < 4; ++p) {
            const int c = p * 256 + t;          // 1024 chunks of 8 bf16
            const int row = c >> 6, col8 = c & 63;
            bf16x8 v = *reinterpret_cast<const bf16x8*>(Ab + row * 512 + col8 * 8);
            f32x4 f0, f1;
            f0.x = (float)v[0]; f0.y = (float)v[1]; f0.z = (float)v[2]; f0.w = (float)v[3];
            f1.x = (float)v[4]; f1.y = (float)v[5]; f1.z = (float)v[6]; f1.w = (float)v[7];
            *reinterpret_cast<f32x4*>(&As[row][col8 * 8])     = f0;
            *reinterpret_cast<f32x4*>(&As[row][col8 * 8 + 4]) = f1;
        }
    } else {
        const float* Af = (const float*)A + (size_t)g * 16 * 512;
        #pragma unroll
        for (int p = 0; p < 8; ++p) {
            const int c = p * 256 + t;          // 2048 chunks of 4 f32
            const int row = c >> 7, col4 = c & 127;
            f32x4 v = *reinterpret_cast<const f32x4*>(Af + row * 512 + col4 * 4);
            *reinterpret_cast<f32x4*>(&As[row][col4 * 4]) = v;
        }
    }
    __syncthreads();
    #pragma unroll
    for (int p = 0; p < 4; ++p) {
        const int c = p * 256 + t;              // 1024 chunks: kt x lane
        const int kt = c >> 6, lane = c & 63;
        const float* src = &As[lane & 15][kt * 32 + (lane >> 4) * 8];
        const f32x4 a0 = *reinterpret_cast<const f32x4*>(src);
        const f32x4 a1 = *reinterpret_cast<const f32x4*>(src + 4);
        bf16x8 v;
        v[0] = (__bf16)a0.x; v[1] = (__bf16)a0.y; v[2] = (__bf16)a0.z; v[3] = (__bf16)a0.w;
        v[4] = (__bf16)a1.x; v[5] = (__bf16)a1.y; v[6] = (__bf16)a1.z; v[7] = (__bf16)a1.w;
        *reinterpret_cast<bf16x8*>(Apk + ((size_t)(g * 16 + kt) * 64 + lane) * 8) = v;
    }
}

// ---- prep: wn_t[n][m] = w_norm[m][n] ----
__global__ void wnorm_kernel(const void* __restrict__ w, const int* __restrict__ flagp,
                             const float* __restrict__ dinv, float* __restrict__ wn_t) {
    const int isbf = *flagp;
    const int idx = blockIdx.x * 256 + threadIdx.x;   // 262144
    const int n = idx >> 9, m = idx & 511;
    float a = ldsel(w, n * 512 + m, isbf) + (m == n ? 1.0f : 0.0f);
    wn_t[idx] = a * dinv[m] * dinv[n];
}

// fragment-major strides (bytes): 16-row-group stride 16 KB, kt stride 1 KB
#define JSTRIDE 16384
#define KSTRIDE 1024

#define LOADW4(dst, base, kt)                                                  \
    _Pragma("unroll")                                                          \
    for (int j = 0; j < 4; ++j)                                                \
        dst[j] = *reinterpret_cast<const bf16x8*>((base) + j * JSTRIDE + (kt) * KSTRIDE);

#define LOADA2(dst, base, kt)                                                  \
    _Pragma("unroll")                                                          \
    for (int i = 0; i < 2; ++i)                                                \
        dst[i] = *reinterpret_cast<const bf16x8*>((base) + i * JSTRIDE + (kt) * KSTRIDE);

#define MFMA_HALF(accset, bset, aset)                                          \
    _Pragma("unroll")                                                          \
    for (int j = 0; j < 4; ++j)                                                \
        _Pragma("unroll")                                                      \
        for (int i = 0; i < 2; ++i)                                            \
            accset[j][i] = __builtin_amdgcn_mfma_f32_16x16x32_bf16(bset[j], aset[i], accset[j][i], 0, 0, 0);

// ---- fused MLP: 16 waves (2 row-groups x 8 col-groups), BM=128; W regs
//      reused across two 32-row halves (accA/accB) -> 16 MFMA per 8 loads ----
template <int PACKED>
__launch_bounds__(1024, 4)
__global__ void fused_mlp(const void* __restrict__ A,      // raw d (fallback path)
                          const bf16_t* __restrict__ Apk,  // fragment-major bf16
                          const bf16_t* __restrict__ W1pk,
                          const bf16_t* __restrict__ W2pk,
                          const float* __restrict__ sc1, const float* __restrict__ sh1,
                          const float* __restrict__ sc2, const float* __restrict__ sh2,
                          const float* __restrict__ wcf,   // 1024 f32
                          const int* __restrict__ flagp,
                          float* __restrict__ U)           // 65536 x 2
{
    __shared__ __align__(16) bf16_t T1s[BM * KDIM];   // 128 KB, XOR-swizzled rows
    __shared__ float UredF[8 * BM * 2];               // 8 KB

    const int isbf = *flagp;
    const int tid = threadIdx.x;
    const int wave = tid >> 6, lane = tid & 63;
    const int wr = wave >> 3, wc = wave & 7;   // rows wr*64..+64, cols wc*64..+64
    const int bm = blockIdx.x;                 // 0..511; rows bm*128..+128
    const int rl = lane & 15, hi = lane >> 4;

    // per-lane fragment-major base pointers (16-row group = JSTRIDE)
    const char* w1base = (const char*)W1pk + ((size_t)(wc * 4) * 16 * 64 + lane) * 16;
    const char* w2base = (const char*)W2pk + ((size_t)(wc * 4) * 16 * 64 + lane) * 16;
    const char* abase  = (const char*)Apk + ((size_t)(bm * 8 + wr * 4) * 16 * 64 + lane) * 16;

    // accA = rows wr*64+0..31 (h=0), accB = rows wr*64+32..63 (h=1)
    f32x4 accA[4][2] = {}, accB[4][2] = {};
    bf16x8 bW[4], aA[2], aB[2];

    // ================= phase 1: T1 = lrelu(bn1(A @ W1^T)) =================
    if (PACKED) {
        for (int kt = 0; kt < 16; ++kt) {
            LOADA2(aA, abase, kt);                   // h=0 (L3-latency first)
            LOADA2(aB, abase + 2 * JSTRIDE, kt);     // h=1
            LOADW4(bW, w1base, kt);                  // L2-resident
            MFMA_HALF(accA, bW, aA);
            MFMA_HALF(accB, bW, aB);
        }
    } else {
        for (int kt = 0; kt < 16; ++kt) {
            LOADW4(bW, w1base, kt);
            #pragma unroll
            for (int h = 0; h < 2; ++h) {
                bf16x8* dst = h ? aB : aA;
                #pragma unroll
                for (int i = 0; i < 2; ++i) {
                    const size_t arow = (size_t)(bm * BM + wr * 64 + h * 32 + i * 16 + rl) * KDIM
                                        + hi * 8 + kt * 32;
                    if (isbf) {
                        dst[i] = *reinterpret_cast<const bf16x8*>((const bf16_t*)A + arow);
                    } else {
                        const f32x4* ap = (const f32x4*)((const float*)A + arow);
                        const f32x4 a0 = ap[0], a1 = ap[1];
                        bf16x8 v;
                        v[0] = (__bf16)a0.x; v[1] = (__bf16)a0.y; v[2] = (__bf16)a0.z; v[3] = (__bf16)a0.w;
                        v[4] = (__bf16)a1.x; v[5] = (__bf16)a1.y; v[6] = (__bf16)a1.z; v[7] = (__bf16)a1.w;
                        dst[i] = v;
                    }
                }
            }
            MFMA_HALF(accA, bW, aA);
            MFMA_HALF(accB, bW, aB);
        }
    }

    // epilogue 1: BN + LReLU; lane holds 4 ADJACENT out-cols -> b64 store
    #pragma unroll
    for (int j = 0; j < 4; ++j) {
        const int gcol0 = wc * 64 + j * 16 + hi * 4;
        const f32x4 s4 = *reinterpret_cast<const f32x4*>(&sc1[gcol0]);
        const f32x4 h4 = *reinterpret_cast<const f32x4*>(&sh1[gcol0]);
        #pragma unroll
        for (int h = 0; h < 2; ++h)
            #pragma unroll
            for (int i = 0; i < 2; ++i) {
                const int row = wr * 64 + h * 32 + i * 16 + rl;
                int off = (row << 10) + (gcol0 << 1);
                off ^= (row & 7) << 4;
                const f32x4 av = h ? accB[j][i] : accA[j][i];
                bf16x4 pk;
                #pragma unroll
                for (int r = 0; r < 4; ++r) {
                    float y = av[r] * s4[r] + h4[r];
                    y = y > 0.f ? y : 0.1f * y;
                    pk[r] = (__bf16)y;
                }
                *reinterpret_cast<bf16x4*>((char*)T1s + off) = pk;
            }
    }
    __syncthreads();

    // ================= phase 2: Y2 = lrelu(bn2(T1 @ W2^T)); U = Y2 @ Wc^T =================
    #pragma unroll
    for (int j = 0; j < 4; ++j)
        #pragma unroll
        for (int i = 0; i < 2; ++i) {
            accA[j][i] = f32x4{0.f, 0.f, 0.f, 0.f};
            accB[j][i] = f32x4{0.f, 0.f, 0.f, 0.f};
        }

    // T1s fragment read for half h, frag i, k-tile kt (XOR-swizzled rows)
    #define LDT1(dst, h, kt)                                                   \
        _Pragma("unroll")                                                      \
        for (int i = 0; i < 2; ++i) {                                          \
            const int row_ = wr * 64 + (h) * 32 + i * 16 + rl;                 \
            int off_ = (row_ << 10) + (kt) * 64 + hi * 16;                     \
            off_ ^= (row_ & 7) << 4;                                           \
            dst[i] = *reinterpret_cast<const bf16x8*>((const char*)T1s + off_);\
        }

    for (int kt = 0; kt < 16; ++kt) {
        LOADW4(bW, w2base, kt);
        LDT1(aA, 0, kt);
        LDT1(aB, 1, kt);
        MFMA_HALF(accA, bW, aA);
        MFMA_HALF(accB, bW, aB);
    }

    // epilogue 2: BN + LReLU + 512->2 projection (in-lane over j,r; shfl over hi)
    float p0A[2] = {0.f, 0.f}, p1A[2] = {0.f, 0.f};
    float p0B[2] = {0.f, 0.f}, p1B[2] = {0.f, 0.f};
    #pragma unroll
    for (int j = 0; j < 4; ++j) {
        const int gcol0 = wc * 64 + j * 16 + hi * 4;
        const f32x4 s4 = *reinterpret_cast<const f32x4*>(&sc2[gcol0]);
        const f32x4 h4 = *reinterpret_cast<const f32x4*>(&sh2[gcol0]);
        const f32x4 w0 = *reinterpret_cast<const f32x4*>(&wcf[gcol0]);
        const f32x4 w1 = *reinterpret_cast<const f32x4*>(&wcf[512 + gcol0]);
        #pragma unroll
        for (int i = 0; i < 2; ++i)
            #pragma unroll
            for (int r = 0; r < 4; ++r) {
                float yA = accA[j][i][r] * s4[r] + h4[r];
                yA = yA > 0.f ? yA : 0.1f * yA;
                p0A[i] += yA * w0[r];
                p1A[i] += yA * w1[r];
                float yB = accB[j][i][r] * s4[r] + h4[r];
                yB = yB > 0.f ? yB : 0.1f * yB;
                p0B[i] += yB * w0[r];
                p1B[i] += yB * w1[r];
            }
    }
    #pragma unroll
    for (int i = 0; i < 2; ++i) {
        float a0 = p0A[i], b0 = p1A[i], a1 = p0B[i], b1 = p1B[i];
        a0 += __shfl_xor(a0, 16, 64);  b0 += __shfl_xor(b0, 16, 64);
        a0 += __shfl_xor(a0, 32, 64);  b0 += __shfl_xor(b0, 32, 64);
        a1 += __shfl_xor(a1, 16, 64);  b1 += __shfl_xor(b1, 16, 64);
        a1 += __shfl_xor(a1, 32, 64);  b1 += __shfl_xor(b1, 32, 64);
        if (hi == 0) {
            const int rowA = wr * 64 + i * 16 + rl;
            const int rowB = rowA + 32;
            UredF[(wc * BM + rowA) * 2]     = a0;
            UredF[(wc * BM + rowA) * 2 + 1] = b0;
            UredF[(wc * BM + rowB) * 2]     = a1;
            UredF[(wc * BM + rowB) * 2 + 1] = b1;
        }
    }
    __syncthreads();
    if (tid < BM * 2) {
        const int row = tid >> 1, c = tid & 1;
        float s = 0.f;
        #pragma unroll
        for (int q = 0; q < 8; ++q) s += UredF[(q * BM + row) * 2 + c];
        U[(size_t)(bm * BM + row) * 2 + c] = s;
    }
    #undef LDT1
}

// ---- GCN on 2-wide features ----
__global__ void gcn_kernel(const float* __restrict__ wn_t, const float* __restrict__ U,
                           const float* __restrict__ bcf, const int* __restrict__ flagp,
                           void* __restrict__ out) {
    const int isbf = *flagp;
    const int wave = threadIdx.x >> 6, lane = threadIdx.x & 63;
    const int task = blockIdx.x * 4 + wave;   // (b, n)
    const int b = task >> 9, n = task & 511;
    const float* wrow = wn_t + n * 512;
    const float* ub = U + b * 1024;
    float a0 = 0.f, a1 = 0.f;
    for (int m = lane; m < 512; m += 64) {
        const float wv = wrow[m];
        a0 += wv * ub[m * 2];
        a1 += wv * ub[m * 2 + 1];
    }
    #pragma unroll
    for (int off = 32; off; off >>= 1) {
        a0 += __shfl_down(a0, off, 64);
        a1 += __shfl_down(a1, off, 64);
    }
    if (lane == 0) {
        const float r0 = a0 + bcf[0];
        const float r1 = a1 + bcf[1];
        if (isbf) {
            ((bf16_t*)out)[task * 2]     = __float2bfloat16(r0);
            ((bf16_t*)out)[task * 2 + 1] = __float2bfloat16(r1);
        } else {
            ((float*)out)[task * 2]     = r0;
            ((float*)out)[task * 2 + 1] = r1;
        }
    }
}

extern "C" void kernel_launch(void* const* d_in, const int* in_sizes, int n_in,
                              void* d_out, int out_size, void* d_ws, size_t ws_size,
                              hipStream_t stream) {
    const void* d   = d_in[0];
    const void* w   = d_in[1];
    const void* W1  = d_in[2];
    const void* b1  = d_in[3];
    const void* g1  = d_in[4];
    const void* be1 = d_in[5];
    const void* m1  = d_in[6];
    const void* v1  = d_in[7];
    const void* W2  = d_in[8];
    const void* b2  = d_in[9];
    const void* g2  = d_in[10];
    const void* be2 = d_in[11];
    const void* m2  = d_in[12];
    const void* v2  = d_in[13];
    const void* Wc  = d_in[14];
    const void* bc  = d_in[15];

    // workspace layout: 3 MB small buffers + 64 MB Apk
    char* ws = (char*)d_ws;
    float*  wn_t = (float*)ws;                         // 1 MB
    bf16_t* W1pk = (bf16_t*)(ws + 0x100000);           // 512 KB (fragment-major)
    bf16_t* W2pk = (bf16_t*)(ws + 0x180000);           // 512 KB
    float*  sc1  = (float*)(ws + 0x200000);
    float*  sh1  = sc1 + 512;
    float*  sc2  = sh1 + 512;
    float*  sh2  = sc2 + 512;
    float*  dinv = sh2 + 512;
    float*  wcf  = (float*)(ws + 0x204000);            // 4 KB
    float*  bcf  = (float*)(ws + 0x205000);
    int*    flag = (int*)(ws + 0x205100);
    float*  U    = (float*)(ws + 0x208000);            // 512 KB
    bf16_t* Apk  = (bf16_t*)(ws + 0x300000);           // 64 MB (fragment-major A)

    const size_t NEED = 0x300000 + (size_t)65536 * 512 * sizeof(bf16_t);
    const bool packed = ws_size >= NEED;

    const int M = 128 * 512;   // 65536 rows

    probe_kernel<<<1, 64, 0, stream>>>(d, flag);
    rowsum_kernel<<<512, 64, 0, stream>>>(w, flag, dinv);
    params_kernel<<<1, 512, 0, stream>>>(g1, b1, m1, v1, be1, g2, b2, m2, v2, be2,
                                         Wc, bc, flag, sc1, sh1, sc2, sh2, wcf, bcf);
    wconv_kernel<<<128, 256, 0, stream>>>(W1, W2, flag, W1pk, W2pk);
    wnorm_kernel<<<1024, 256, 0, stream>>>(w, flag, dinv, wn_t);

    if (packed) {
        aconv_kernel<<<M / 16, 256, 0, stream>>>(d, flag, Apk);
        fused_mlp<1><<<M / BM, 1024, 0, stream>>>(d, Apk, W1pk, W2pk,
                                                  sc1, sh1, sc2, sh2, wcf, flag, U);
    } else {
        fused_mlp<0><<<M / BM, 1024, 0, stream>>>(d, Apk, W1pk, W2pk,
                                                  sc1, sh1, sc2, sh2, wcf, flag, U);
    }

    gcn_kernel<<<M / 4, 256, 0, stream>>>(wn_t, U, bcf, flag, d_out);
}

// Round 11
// 146.720 us; speedup vs baseline: 2.5114x; 1.1276x over previous
//
#include <hip/hip_runtime.h>
#include <hip/hip_bf16.h>

// Sggnn_gcn — fused 2x(Linear512+BN+LReLU) + Wc projection, then GCN on 2-wide
// features. Restructuring: (w_norm^T @ t) @ Wc^T == w_norm^T @ (t @ Wc^T).
// v11: aconv pass FUSED into fused_mlp. Per kt, waves 0-7 stage the raw
// f32/bf16 A-tile coalesced->reg->cvt->fragment-major LDS (double-buffered,
// T14 issue-early/write-late so loads fly across the barrier). Compute core
// = v10 (BM=128, accA/accB W-reuse, fragment-major W global->reg from L2).
// Kills aconv's 192 MB traffic + ~30us dispatch. #pragma unroll 1 on K-loops
// to stop unroll-hoist VGPR blowup (v10's 73 MB spill).

typedef __hip_bfloat16 bf16_t;
typedef __bf16 bf16x8 __attribute__((ext_vector_type(8)));
typedef __bf16 bf16x4 __attribute__((ext_vector_type(4)));
typedef float f32x4 __attribute__((ext_vector_type(4)));

#define KDIM 512
#define BM 128     // rows per block

// load element i of a logically-f32 vector that may be stored as bf16
__device__ __forceinline__ float ldsel(const void* p, int i, int isbf) {
    return isbf ? __bfloat162float(((const bf16_t*)p)[i]) : ((const float*)p)[i];
}

// ---- probe: detect dtype of d (bf16 vs f32) from exponent statistics ----
__global__ void probe_kernel(const void* __restrict__ d, int* __restrict__ flag) {
    const unsigned short* u = (const unsigned short*)d;
    const int l = threadIdx.x;   // 64
    int cnt = 0;
    for (int i = l; i < 256; i += 64) {
        const int e = (u[i] >> 7) & 0xFF;
        cnt += (e >= 118 && e <= 129) ? 1 : 0;
    }
    #pragma unroll
    for (int off = 32; off; off >>= 1) cnt += __shfl_down(cnt, off, 64);
    if (l == 0) *flag = (cnt >= 200) ? 1 : 0;   // bf16 ~255, f32 ~134
}

// ---- prep: rowsum of adj = w + I  ->  d_inv_sqrt ----
__global__ void rowsum_kernel(const void* __restrict__ w, const int* __restrict__ flagp,
                              float* __restrict__ dinv) {
    const int isbf = *flagp;
    const int i = blockIdx.x;
    const int l = threadIdx.x;
    float s = 0.f;
    for (int j = l; j < 512; j += 64) s += ldsel(w, i * 512 + j, isbf);
    #pragma unroll
    for (int off = 32; off; off >>= 1) s += __shfl_down(s, off, 64);
    if (l == 0) dinv[i] = 1.0f / sqrtf(s + 1.0f);
}

// ---- prep: fold BN -> scale/shift; canonicalize Wc, bc to f32 ----
__global__ void params_kernel(const void* g1, const void* b1, const void* m1,
                              const void* v1, const void* be1,
                              const void* g2, const void* b2, const void* m2,
                              const void* v2, const void* be2,
                              const void* Wc, const void* bc,
                              const int* __restrict__ flagp,
                              float* sc1, float* sh1, float* sc2, float* sh2,
                              float* wcf, float* bcf) {
    const int isbf = *flagp;
    const int i = threadIdx.x;  // 512
    float s1 = ldsel(g1, i, isbf) / sqrtf(ldsel(v1, i, isbf) + 1e-5f);
    sc1[i] = s1;
    sh1[i] = (ldsel(b1, i, isbf) - ldsel(m1, i, isbf)) * s1 + ldsel(be1, i, isbf);
    float s2 = ldsel(g2, i, isbf) / sqrtf(ldsel(v2, i, isbf) + 1e-5f);
    sc2[i] = s2;
    sh2[i] = (ldsel(b2, i, isbf) - ldsel(m2, i, isbf)) * s2 + ldsel(be2, i, isbf);
    wcf[i] = ldsel(Wc, i, isbf);
    wcf[512 + i] = ldsel(Wc, 512 + i, isbf);
    if (i < 2) bcf[i] = ldsel(bc, i, isbf);
}

// ---- prep: W1,W2 -> bf16 in FRAGMENT-MAJOR order.
// chunk t = ((c16*16 + kt)*64 + lane); data = W[c16*16 + (lane&15)][kt*32 + (lane>>4)*8 ..+8]
__global__ void wconv_kernel(const void* __restrict__ W1, const void* __restrict__ W2,
                             const int* __restrict__ flagp,
                             bf16_t* __restrict__ W1pk, bf16_t* __restrict__ W2pk) {
    const int isbf = *flagp;
    const int t = blockIdx.x * 256 + threadIdx.x;   // 0..32767
    const int lane = t & 63;
    const int kt = (t >> 6) & 15;
    const int c16 = t >> 10;
    const int src = (c16 * 16 + (lane & 15)) * 512 + kt * 32 + (lane >> 4) * 8;
    bf16x8 v1, v2;
    #pragma unroll
    for (int e = 0; e < 8; ++e) {
        v1[e] = (__bf16)ldsel(W1, src + e, isbf);
        v2[e] = (__bf16)ldsel(W2, src + e, isbf);
    }
    *reinterpret_cast<bf16x8*>(W1pk + (size_t)t * 8) = v1;
    *reinterpret_cast<bf16x8*>(W2pk + (size_t)t * 8) = v2;
}

// ---- prep: wn_t[n][m] = w_norm[m][n] ----
__global__ void wnorm_kernel(const void* __restrict__ w, const int* __restrict__ flagp,
                             const float* __restrict__ dinv, float* __restrict__ wn_t) {
    const int isbf = *flagp;
    const int idx = blockIdx.x * 256 + threadIdx.x;   // 262144
    const int n = idx >> 9, m = idx & 511;
    float a = ldsel(w, n * 512 + m, isbf) + (m == n ? 1.0f : 0.0f);
    wn_t[idx] = a * dinv[m] * dinv[n];
}

// fragment-major strides (bytes): 16-row-group stride 16 KB, kt stride 1 KB
#define JSTRIDE 16384
#define KSTRIDE 1024

#define LOADW4(dst, base, kt)                                                  \
    _Pragma("unroll")                                                          \
    for (int j = 0; j < 4; ++j)                                                \
        dst[j] = *reinterpret_cast<const bf16x8*>((base) + j * JSTRIDE + (kt) * KSTRIDE);

#define MFMA_HALF(accset, bset, aset)                                          \
    _Pragma("unroll")                                                          \
    for (int j = 0; j < 4; ++j)                                                \
        _Pragma("unroll")                                                      \
        for (int i = 0; i < 2; ++i)                                            \
            accset[j][i] = __builtin_amdgcn_mfma_f32_16x16x32_bf16(bset[j], aset[i], accset[j][i], 0, 0, 0);

// issue global loads for A k-tile kt into register set S (staging waves 0-7)
#define LOADSTG(S, kt)                                                         \
    if (tid < 512) {                                                           \
        if (isbf) {                                                            \
            sb##S = *reinterpret_cast<const bf16x8*>((const bf16_t*)A + sgbase + (size_t)(kt) * 32); \
        } else {                                                               \
            const f32x4* p_ = (const f32x4*)((const float*)A + sgbase + (size_t)(kt) * 32); \
            sf0##S = p_[0]; sf1##S = p_[1];                                    \
        }                                                                      \
    }

// convert + ds_write register set S into Astage buffer bufi (fragment-major)
#define STW(S, bufi)                                                           \
    if (tid < 512) {                                                           \
        bf16x8 v_;                                                             \
        if (isbf) { v_ = sb##S; }                                              \
        else {                                                                 \
            v_[0] = (__bf16)sf0##S.x; v_[1] = (__bf16)sf0##S.y;                \
            v_[2] = (__bf16)sf0##S.z; v_[3] = (__bf16)sf0##S.w;                \
            v_[4] = (__bf16)sf1##S.x; v_[5] = (__bf16)sf1##S.y;                \
            v_[6] = (__bf16)sf1##S.z; v_[7] = (__bf16)sf1##S.w;                \
        }                                                                      \
        *reinterpret_cast<bf16x8*>((char*)Astage + (bufi) * 8192 + sldsoff) = v_; \
    }

// ds_read 4 A-frags from Astage[bufi] + load 4 W-frags + 16 MFMA
#define COMPUTE(kt, bufi, wbase)                                               \
    {                                                                          \
        const char* ab_ = (const char*)Astage + (bufi) * 8192 + lane * 16;     \
        bf16x8 aA_[2], aB_[2], bW_[4];                                         \
        aA_[0] = *reinterpret_cast<const bf16x8*>(ab_ + (wr * 4 + 0) * 1024);  \
        aA_[1] = *reinterpret_cast<const bf16x8*>(ab_ + (wr * 4 + 1) * 1024);  \
        aB_[0] = *reinterpret_cast<const bf16x8*>(ab_ + (wr * 4 + 2) * 1024);  \
        aB_[1] = *reinterpret_cast<const bf16x8*>(ab_ + (wr * 4 + 3) * 1024);  \
        LOADW4(bW_, wbase, kt);                                                \
        MFMA_HALF(accA, bW_, aA_);                                             \
        MFMA_HALF(accB, bW_, aB_);                                             \
    }

// ---- fused MLP: 16 waves, BM=128; A staged in-kernel from raw d ----
__launch_bounds__(1024, 4)
__global__ void fused_mlp(const void* __restrict__ A,      // d: f32 or bf16, 65536x512
                          const bf16_t* __restrict__ W1pk, // fragment-major bf16
                          const bf16_t* __restrict__ W2pk,
                          const float* __restrict__ sc1, const float* __restrict__ sh1,
                          const float* __restrict__ sc2, const float* __restrict__ sh2,
                          const float* __restrict__ wcf,   // 1024 f32
                          const int* __restrict__ flagp,
                          float* __restrict__ U)           // 65536 x 2
{
    __shared__ __align__(16) bf16_t T1s[BM * KDIM];      // 128 KB, XOR-swizzled rows
    __shared__ __align__(16) bf16_t Astage[2][BM * 32];  // 2 x 8 KB fragment-major
    float* UredF = (float*)Astage;                       // 8 KB, reused after phase 1

    const int isbf = *flagp;
    const int tid = threadIdx.x;
    const int wave = tid >> 6, lane = tid & 63;
    const int wr = wave >> 3, wc = wave & 7;   // rows wr*64..+64, cols wc*64..+64
    const int bm = blockIdx.x;                 // 0..511; rows bm*128..+128
    const int rl = lane & 15, hi = lane >> 4;

    // per-lane fragment-major W base pointers
    const char* w1base = (const char*)W1pk + ((size_t)(wc * 4) * 16 * 64 + lane) * 16;
    const char* w2base = (const char*)W2pk + ((size_t)(wc * 4) * 16 * 64 + lane) * 16;

    // staging mapping (waves 0-7): row srow, 8-elem k-chunk skc
    const int srow = tid >> 2;                 // 0..127 (valid for tid<512)
    const int skc = tid & 3;
    const size_t sgbase = (size_t)(bm * BM + srow) * KDIM + skc * 8;
    const int sldsoff = (srow >> 4) * 1024 + ((srow & 15) + skc * 16) * 16;

    f32x4 accA[4][2] = {}, accB[4][2] = {};
    f32x4 sf0A, sf1A, sf0B, sf1B;
    bf16x8 sbA, sbB;

    // ================= phase 1: T1 = lrelu(bn1(A @ W1^T)) =================
    LOADSTG(A, 0);
    STW(A, 0);          // vmcnt wait inside; buf0 <- kt0
    LOADSTG(B, 1);      // kt1 in flight
    __syncthreads();    // buf0 visible

    #pragma unroll 1
    for (int kt = 0; kt < 16; kt += 2) {
        // even step kt: compute buf[kt&1]; commit kt+1 -> buf[(kt+1)&1]
        if (kt + 2 < 16) LOADSTG(A, kt + 2);
        COMPUTE(kt, kt & 1, w1base);
        STW(B, (kt + 1) & 1);
        __syncthreads();
        // odd step kt+1
        if (kt + 3 < 16) LOADSTG(B, kt + 3);
        COMPUTE(kt + 1, (kt + 1) & 1, w1base);
        if (kt + 2 < 16) STW(A, kt & 1);
        __syncthreads();
    }

    // epilogue 1: BN + LReLU; lane holds 4 ADJACENT out-cols -> b64 store
    #pragma unroll
    for (int j = 0; j < 4; ++j) {
        const int gcol0 = wc * 64 + j * 16 + hi * 4;
        const f32x4 s4 = *reinterpret_cast<const f32x4*>(&sc1[gcol0]);
        const f32x4 h4 = *reinterpret_cast<const f32x4*>(&sh1[gcol0]);
        #pragma unroll
        for (int h = 0; h < 2; ++h)
            #pragma unroll
            for (int i = 0; i < 2; ++i) {
                const int row = wr * 64 + h * 32 + i * 16 + rl;
                int off = (row << 10) + (gcol0 << 1);
                off ^= (row & 7) << 4;
                const f32x4 av = h ? accB[j][i] : accA[j][i];
                bf16x4 pk;
                #pragma unroll
                for (int r = 0; r < 4; ++r) {
                    float y = av[r] * s4[r] + h4[r];
                    y = y > 0.f ? y : 0.1f * y;
                    pk[r] = (__bf16)y;
                }
                *reinterpret_cast<bf16x4*>((char*)T1s + off) = pk;
            }
    }
    __syncthreads();

    // ================= phase 2: Y2 = lrelu(bn2(T1 @ W2^T)); U = Y2 @ Wc^T =================
    #pragma unroll
    for (int j = 0; j < 4; ++j)
        #pragma unroll
        for (int i = 0; i < 2; ++i) {
            accA[j][i] = f32x4{0.f, 0.f, 0.f, 0.f};
            accB[j][i] = f32x4{0.f, 0.f, 0.f, 0.f};
        }

    #define LDT1(dst, h, kt)                                                   \
        _Pragma("unroll")                                                      \
        for (int i = 0; i < 2; ++i) {                                          \
            const int row_ = wr * 64 + (h) * 32 + i * 16 + rl;                 \
            int off_ = (row_ << 10) + (kt) * 64 + hi * 16;                     \
            off_ ^= (row_ & 7) << 4;                                           \
            dst[i] = *reinterpret_cast<const bf16x8*>((const char*)T1s + off_);\
        }

    #pragma unroll 1
    for (int kt = 0; kt < 16; ++kt) {
        bf16x8 bW[4], aA[2], aB[2];
        LOADW4(bW, w2base, kt);
        LDT1(aA, 0, kt);
        LDT1(aB, 1, kt);
        MFMA_HALF(accA, bW, aA);
        MFMA_HALF(accB, bW, aB);
    }

    // epilogue 2: BN + LReLU + 512->2 projection (in-lane over j,r; shfl over hi)
    float p0A[2] = {0.f, 0.f}, p1A[2] = {0.f, 0.f};
    float p0B[2] = {0.f, 0.f}, p1B[2] = {0.f, 0.f};
    #pragma unroll
    for (int j = 0; j < 4; ++j) {
        const int gcol0 = wc * 64 + j * 16 + hi * 4;
        const f32x4 s4 = *reinterpret_cast<const f32x4*>(&sc2[gcol0]);
        const f32x4 h4 = *reinterpret_cast<const f32x4*>(&sh2[gcol0]);
        const f32x4 w0 = *reinterpret_cast<const f32x4*>(&wcf[gcol0]);
        const f32x4 w1 = *reinterpret_cast<const f32x4*>(&wcf[512 + gcol0]);
        #pragma unroll
        for (int i = 0; i < 2; ++i)
            #pragma unroll
            for (int r = 0; r < 4; ++r) {
                float yA = accA[j][i][r] * s4[r] + h4[r];
                yA = yA > 0.f ? yA : 0.1f * yA;
                p0A[i] += yA * w0[r];
                p1A[i] += yA * w1[r];
                float yB = accB[j][i][r] * s4[r] + h4[r];
                yB = yB > 0.f ? yB : 0.1f * yB;
                p0B[i] += yB * w0[r];
                p1B[i] += yB * w1[r];
            }
    }
    __syncthreads();   // Astage reads long done; order before UredF overlay
    #pragma unroll
    for (int i = 0; i < 2; ++i) {
        float a0 = p0A[i], b0 = p1A[i], a1 = p0B[i], b1 = p1B[i];
        a0 += __shfl_xor(a0, 16, 64);  b0 += __shfl_xor(b0, 16, 64);
        a0 += __shfl_xor(a0, 32, 64);  b0 += __shfl_xor(b0, 32, 64);
        a1 += __shfl_xor(a1, 16, 64);  b1 += __shfl_xor(b1, 16, 64);
        a1 += __shfl_xor(a1, 32, 64);  b1 += __shfl_xor(b1, 32, 64);
        if (hi == 0) {
            const int rowA = wr * 64 + i * 16 + rl;
            const int rowB = rowA + 32;
            UredF[(wc * BM + rowA) * 2]     = a0;
            UredF[(wc * BM + rowA) * 2 + 1] = b0;
            UredF[(wc * BM + rowB) * 2]     = a1;
            UredF[(wc * BM + rowB) * 2 + 1] = b1;
        }
    }
    __syncthreads();
    if (tid < BM * 2) {
        const int row = tid >> 1, c = tid & 1;
        float s = 0.f;
        #pragma unroll
        for (int q = 0; q < 8; ++q) s += UredF[(q * BM + row) * 2 + c];
        U[(size_t)(bm * BM + row) * 2 + c] = s;
    }
    #undef LDT1
}

// ---- GCN on 2-wide features ----
__global__ void gcn_kernel(const float* __restrict__ wn_t, const float* __restrict__ U,
                           const float* __restrict__ bcf, const int* __restrict__ flagp,
                           void* __restrict__ out) {
    const int isbf = *flagp;
    const int wave = threadIdx.x >> 6, lane = threadIdx.x & 63;
    const int task = blockIdx.x * 4 + wave;   // (b, n)
    const int b = task >> 9, n = task & 511;
    const float* wrow = wn_t + n * 512;
    const float* ub = U + b * 1024;
    float a0 = 0.f, a1 = 0.f;
    for (int m = lane; m < 512; m += 64) {
        const float wv = wrow[m];
        a0 += wv * ub[m * 2];
        a1 += wv * ub[m * 2 + 1];
    }
    #pragma unroll
    for (int off = 32; off; off >>= 1) {
        a0 += __shfl_down(a0, off, 64);
        a1 += __shfl_down(a1, off, 64);
    }
    if (lane == 0) {
        const float r0 = a0 + bcf[0];
        const float r1 = a1 + bcf[1];
        if (isbf) {
            ((bf16_t*)out)[task * 2]     = __float2bfloat16(r0);
            ((bf16_t*)out)[task * 2 + 1] = __float2bfloat16(r1);
        } else {
            ((float*)out)[task * 2]     = r0;
            ((float*)out)[task * 2 + 1] = r1;
        }
    }
}

extern "C" void kernel_launch(void* const* d_in, const int* in_sizes, int n_in,
                              void* d_out, int out_size, void* d_ws, size_t ws_size,
                              hipStream_t stream) {
    const void* d   = d_in[0];
    const void* w   = d_in[1];
    const void* W1  = d_in[2];
    const void* b1  = d_in[3];
    const void* g1  = d_in[4];
    const void* be1 = d_in[5];
    const void* m1  = d_in[6];
    const void* v1  = d_in[7];
    const void* W2  = d_in[8];
    const void* b2  = d_in[9];
    const void* g2  = d_in[10];
    const void* be2 = d_in[11];
    const void* m2  = d_in[12];
    const void* v2  = d_in[13];
    const void* Wc  = d_in[14];
    const void* bc  = d_in[15];

    // workspace layout: ~2.6 MB total (Apk eliminated)
    char* ws = (char*)d_ws;
    float*  wn_t = (float*)ws;                         // 1 MB
    bf16_t* W1pk = (bf16_t*)(ws + 0x100000);           // 512 KB (fragment-major)
    bf16_t* W2pk = (bf16_t*)(ws + 0x180000);           // 512 KB
    float*  sc1  = (float*)(ws + 0x200000);
    float*  sh1  = sc1 + 512;
    float*  sc2  = sh1 + 512;
    float*  sh2  = sc2 + 512;
    float*  dinv = sh2 + 512;
    float*  wcf  = (float*)(ws + 0x204000);            // 4 KB
    float*  bcf  = (float*)(ws + 0x205000);
    int*    flag = (int*)(ws + 0x205100);
    float*  U    = (float*)(ws + 0x208000);            // 512 KB

    const int M = 128 * 512;   // 65536 rows

    probe_kernel<<<1, 64, 0, stream>>>(d, flag);
    rowsum_kernel<<<512, 64, 0, stream>>>(w, flag, dinv);
    params_kernel<<<1, 512, 0, stream>>>(g1, b1, m1, v1, be1, g2, b2, m2, v2, be2,
                                         Wc, bc, flag, sc1, sh1, sc2, sh2, wcf, bcf);
    wconv_kernel<<<128, 256, 0, stream>>>(W1, W2, flag, W1pk, W2pk);
    wnorm_kernel<<<1024, 256, 0, stream>>>(w, flag, dinv, wn_t);

    fused_mlp<<<M / BM, 1024, 0, stream>>>(d, W1pk, W2pk,
                                           sc1, sh1, sc2, sh2, wcf, flag, U);

    gcn_kernel<<<M / 4, 256, 0, stream>>>(wn_t, U, bcf, flag, d_out);
}

// Round 12
// 137.396 us; speedup vs baseline: 2.6818x; 1.0679x over previous
//
#include <hip/hip_runtime.h>
#include <hip/hip_bf16.h>

// Sggnn_gcn — fused 2x(Linear512+BN+LReLU) + Wc projection, then GCN on 2-wide
// features. Restructuring: (w_norm^T @ t) @ Wc^T == w_norm^T @ (t @ Wc^T).
// v12 = v11 (in-kernel A staging, BM=128, accA/accB W-reuse) +
//   * depth-1 W prefetch: bW0/bW1 alternate per kt (static names, unroll-2
//     bodies) so the 4 L2 W-loads are in flight during the prior 16 MFMAs.
//   * single-set A staging using ALL 1024 threads (16B/thread): issued one
//     full kt-step (~1200cyc) before the ds_write -> HBM latency covered.
//   * A-frag ds_reads split 2+2 around the MFMA halves (fewer live regs).
// Reg budget: 64 AGPR acc + 16 bW0 + 16 bW1 + 4 staging + ~8 transients
// + addressing ~= 120 <= 128 (4 waves/SIMD).

typedef __hip_bfloat16 bf16_t;
typedef __bf16 bf16x8 __attribute__((ext_vector_type(8)));
typedef __bf16 bf16x4 __attribute__((ext_vector_type(4)));
typedef float f32x4 __attribute__((ext_vector_type(4)));

#define KDIM 512
#define BM 128     // rows per block

__device__ __forceinline__ float ldsel(const void* p, int i, int isbf) {
    return isbf ? __bfloat162float(((const bf16_t*)p)[i]) : ((const float*)p)[i];
}

// ---- probe: detect dtype of d (bf16 vs f32) from exponent statistics ----
__global__ void probe_kernel(const void* __restrict__ d, int* __restrict__ flag) {
    const unsigned short* u = (const unsigned short*)d;
    const int l = threadIdx.x;   // 64
    int cnt = 0;
    for (int i = l; i < 256; i += 64) {
        const int e = (u[i] >> 7) & 0xFF;
        cnt += (e >= 118 && e <= 129) ? 1 : 0;
    }
    #pragma unroll
    for (int off = 32; off; off >>= 1) cnt += __shfl_down(cnt, off, 64);
    if (l == 0) *flag = (cnt >= 200) ? 1 : 0;   // bf16 ~255, f32 ~134
}

// ---- prep: rowsum of adj = w + I  ->  d_inv_sqrt ----
__global__ void rowsum_kernel(const void* __restrict__ w, const int* __restrict__ flagp,
                              float* __restrict__ dinv) {
    const int isbf = *flagp;
    const int i = blockIdx.x;
    const int l = threadIdx.x;
    float s = 0.f;
    for (int j = l; j < 512; j += 64) s += ldsel(w, i * 512 + j, isbf);
    #pragma unroll
    for (int off = 32; off; off >>= 1) s += __shfl_down(s, off, 64);
    if (l == 0) dinv[i] = 1.0f / sqrtf(s + 1.0f);
}

// ---- prep: fold BN -> scale/shift; canonicalize Wc, bc to f32 ----
__global__ void params_kernel(const void* g1, const void* b1, const void* m1,
                              const void* v1, const void* be1,
                              const void* g2, const void* b2, const void* m2,
                              const void* v2, const void* be2,
                              const void* Wc, const void* bc,
                              const int* __restrict__ flagp,
                              float* sc1, float* sh1, float* sc2, float* sh2,
                              float* wcf, float* bcf) {
    const int isbf = *flagp;
    const int i = threadIdx.x;  // 512
    float s1 = ldsel(g1, i, isbf) / sqrtf(ldsel(v1, i, isbf) + 1e-5f);
    sc1[i] = s1;
    sh1[i] = (ldsel(b1, i, isbf) - ldsel(m1, i, isbf)) * s1 + ldsel(be1, i, isbf);
    float s2 = ldsel(g2, i, isbf) / sqrtf(ldsel(v2, i, isbf) + 1e-5f);
    sc2[i] = s2;
    sh2[i] = (ldsel(b2, i, isbf) - ldsel(m2, i, isbf)) * s2 + ldsel(be2, i, isbf);
    wcf[i] = ldsel(Wc, i, isbf);
    wcf[512 + i] = ldsel(Wc, 512 + i, isbf);
    if (i < 2) bcf[i] = ldsel(bc, i, isbf);
}

// ---- prep: W1,W2 -> bf16 in FRAGMENT-MAJOR order ----
__global__ void wconv_kernel(const void* __restrict__ W1, const void* __restrict__ W2,
                             const int* __restrict__ flagp,
                             bf16_t* __restrict__ W1pk, bf16_t* __restrict__ W2pk) {
    const int isbf = *flagp;
    const int t = blockIdx.x * 256 + threadIdx.x;   // 0..32767
    const int lane = t & 63;
    const int kt = (t >> 6) & 15;
    const int c16 = t >> 10;
    const int src = (c16 * 16 + (lane & 15)) * 512 + kt * 32 + (lane >> 4) * 8;
    bf16x8 v1, v2;
    #pragma unroll
    for (int e = 0; e < 8; ++e) {
        v1[e] = (__bf16)ldsel(W1, src + e, isbf);
        v2[e] = (__bf16)ldsel(W2, src + e, isbf);
    }
    *reinterpret_cast<bf16x8*>(W1pk + (size_t)t * 8) = v1;
    *reinterpret_cast<bf16x8*>(W2pk + (size_t)t * 8) = v2;
}

// ---- prep: wn_t[n][m] = w_norm[m][n] ----
__global__ void wnorm_kernel(const void* __restrict__ w, const int* __restrict__ flagp,
                             const float* __restrict__ dinv, float* __restrict__ wn_t) {
    const int isbf = *flagp;
    const int idx = blockIdx.x * 256 + threadIdx.x;   // 262144
    const int n = idx >> 9, m = idx & 511;
    float a = ldsel(w, n * 512 + m, isbf) + (m == n ? 1.0f : 0.0f);
    wn_t[idx] = a * dinv[m] * dinv[n];
}

#define JSTRIDE 16384
#define KSTRIDE 1024

#define LOADW4(dst, base, kt)                                                  \
    _Pragma("unroll")                                                          \
    for (int j = 0; j < 4; ++j)                                                \
        dst[j] = *reinterpret_cast<const bf16x8*>((base) + j * JSTRIDE + (kt) * KSTRIDE);

#define MFMA_HALF(accset, bset, aset)                                          \
    _Pragma("unroll")                                                          \
    for (int j = 0; j < 4; ++j)                                                \
        _Pragma("unroll")                                                      \
        for (int i = 0; i < 2; ++i)                                            \
            accset[j][i] = __builtin_amdgcn_mfma_f32_16x16x32_bf16(bset[j], aset[i], accset[j][i], 0, 0, 0);

// issue staging loads for A k-tile kt (all 1024 threads, 16B f32 / 8B bf16)
#define SISSUE(kt)                                                             \
    {                                                                          \
        if (isbf) sb = *reinterpret_cast<const bf16x4*>((const bf16_t*)A + sgbase + (size_t)(kt) * 32); \
        else      sf = *reinterpret_cast<const f32x4*>((const float*)A + sgbase + (size_t)(kt) * 32);  \
    }

// convert + ds_write the staged regs into Astage[bufi] (fragment-major)
#define SWRITE(bufi)                                                           \
    {                                                                          \
        bf16x4 v_;                                                             \
        if (isbf) { v_ = sb; }                                                 \
        else {                                                                 \
            v_[0] = (__bf16)sf.x; v_[1] = (__bf16)sf.y;                        \
            v_[2] = (__bf16)sf.z; v_[3] = (__bf16)sf.w;                        \
        }                                                                      \
        *reinterpret_cast<bf16x4*>((char*)Astage + (bufi) * 8192 + sldsoff) = v_; \
    }

// ds_read A frags (2+2 split) + 16 MFMA with the given prefetched W set
#define COMPUTE2(bufi, bWs)                                                    \
    {                                                                          \
        const char* ab_ = (const char*)Astage + (bufi) * 8192 + lane * 16;     \
        bf16x8 aT_[2];                                                         \
        aT_[0] = *reinterpret_cast<const bf16x8*>(ab_ + (wr * 4 + 0) * 1024);  \
        aT_[1] = *reinterpret_cast<const bf16x8*>(ab_ + (wr * 4 + 1) * 1024);  \
        MFMA_HALF(accA, bWs, aT_);                                             \
        aT_[0] = *reinterpret_cast<const bf16x8*>(ab_ + (wr * 4 + 2) * 1024);  \
        aT_[1] = *reinterpret_cast<const bf16x8*>(ab_ + (wr * 4 + 3) * 1024);  \
        MFMA_HALF(accB, bWs, aT_);                                             \
    }

// ---- fused MLP: 16 waves, BM=128; A staged in-kernel; W depth-1 prefetch ----
__launch_bounds__(1024, 4)
__global__ void fused_mlp(const void* __restrict__ A,      // d: f32 or bf16, 65536x512
                          const bf16_t* __restrict__ W1pk, // fragment-major bf16
                          const bf16_t* __restrict__ W2pk,
                          const float* __restrict__ sc1, const float* __restrict__ sh1,
                          const float* __restrict__ sc2, const float* __restrict__ sh2,
                          const float* __restrict__ wcf,   // 1024 f32
                          const int* __restrict__ flagp,
                          float* __restrict__ U)           // 65536 x 2
{
    __shared__ __align__(16) bf16_t T1s[BM * KDIM];      // 128 KB, XOR-swizzled rows
    __shared__ __align__(16) bf16_t Astage[2][BM * 32];  // 2 x 8 KB fragment-major
    float* UredF = (float*)Astage;                       // 8 KB, reused after phase 1

    const int isbf = *flagp;
    const int tid = threadIdx.x;
    const int wave = tid >> 6, lane = tid & 63;
    const int wr = wave >> 3, wc = wave & 7;   // rows wr*64..+64, cols wc*64..+64
    const int bm = blockIdx.x;                 // 0..511; rows bm*128..+128
    const int rl = lane & 15, hi = lane >> 4;

    const char* w1base = (const char*)W1pk + ((size_t)(wc * 4) * 16 * 64 + lane) * 16;
    const char* w2base = (const char*)W2pk + ((size_t)(wc * 4) * 16 * 64 + lane) * 16;

    // staging mapping (ALL 1024 threads): row srow, 4-elem chunk sk4
    const int srow = tid >> 3;                 // 0..127
    const int sk4 = tid & 7;                   // 0..7 (4 elems each)
    const size_t sgbase = (size_t)(bm * BM + srow) * KDIM + sk4 * 4;
    const int sldsoff = (srow >> 4) * 1024 + ((srow & 15) + (sk4 >> 1) * 16) * 16
                        + (sk4 & 1) * 8;

    f32x4 accA[4][2] = {}, accB[4][2] = {};
    bf16x8 bW0[4], bW1[4];
    f32x4 sf;
    bf16x4 sb;

    // ================= phase 1: T1 = lrelu(bn1(A @ W1^T)) =================
    SISSUE(0);
    SWRITE(0);            // waits vmcnt via dependency; buf0 <- kt0
    SISSUE(1);
    LOADW4(bW0, w1base, 0);
    __syncthreads();      // buf0 visible

    #pragma unroll 1
    for (int kt = 0; kt < 16; kt += 2) {
        // ---- even body: compute kt with bW0 / buf[kt&1] ----
        LOADW4(bW1, w1base, kt + 1);           // prefetch next W
        COMPUTE2(kt & 1, bW0);
        SWRITE((kt + 1) & 1);                  // sf holds kt+1
        if (kt + 2 < 16) SISSUE(kt + 2);
        __syncthreads();
        // ---- odd body: compute kt+1 with bW1 / buf[(kt+1)&1] ----
        if (kt + 2 < 16) LOADW4(bW0, w1base, kt + 2);
        COMPUTE2((kt + 1) & 1, bW1);
        if (kt + 2 < 16) SWRITE((kt + 2) & 1); // sf holds kt+2
        if (kt + 3 < 16) SISSUE(kt + 3);
        __syncthreads();
    }

    // epilogue 1: BN + LReLU; lane holds 4 ADJACENT out-cols -> b64 store
    #pragma unroll
    for (int j = 0; j < 4; ++j) {
        const int gcol0 = wc * 64 + j * 16 + hi * 4;
        const f32x4 s4 = *reinterpret_cast<const f32x4*>(&sc1[gcol0]);
        const f32x4 h4 = *reinterpret_cast<const f32x4*>(&sh1[gcol0]);
        #pragma unroll
        for (int h = 0; h < 2; ++h)
            #pragma unroll
            for (int i = 0; i < 2; ++i) {
                const int row = wr * 64 + h * 32 + i * 16 + rl;
                int off = (row << 10) + (gcol0 << 1);
                off ^= (row & 7) << 4;
                const f32x4 av = h ? accB[j][i] : accA[j][i];
                bf16x4 pk;
                #pragma unroll
                for (int r = 0; r < 4; ++r) {
                    float y = av[r] * s4[r] + h4[r];
                    y = y > 0.f ? y : 0.1f * y;
                    pk[r] = (__bf16)y;
                }
                *reinterpret_cast<bf16x4*>((char*)T1s + off) = pk;
            }
    }
    __syncthreads();

    // ================= phase 2: Y2 = lrelu(bn2(T1 @ W2^T)); U = Y2 @ Wc^T =================
    #pragma unroll
    for (int j = 0; j < 4; ++j)
        #pragma unroll
        for (int i = 0; i < 2; ++i) {
            accA[j][i] = f32x4{0.f, 0.f, 0.f, 0.f};
            accB[j][i] = f32x4{0.f, 0.f, 0.f, 0.f};
        }

    // T1s frag read (2+2 split) + 16 MFMA with given W set
    #define COMPT1(kt, bWs)                                                    \
        {                                                                      \
            bf16x8 aT_[2];                                                     \
            _Pragma("unroll")                                                  \
            for (int i = 0; i < 2; ++i) {                                      \
                const int row_ = wr * 64 + i * 16 + rl;                        \
                int off_ = (row_ << 10) + (kt) * 64 + hi * 16;                 \
                off_ ^= (row_ & 7) << 4;                                       \
                aT_[i] = *reinterpret_cast<const bf16x8*>((const char*)T1s + off_); \
            }                                                                  \
            MFMA_HALF(accA, bWs, aT_);                                         \
            _Pragma("unroll")                                                  \
            for (int i = 0; i < 2; ++i) {                                      \
                const int row_ = wr * 64 + 32 + i * 16 + rl;                   \
                int off_ = (row_ << 10) + (kt) * 64 + hi * 16;                 \
                off_ ^= (row_ & 7) << 4;                                       \
                aT_[i] = *reinterpret_cast<const bf16x8*>((const char*)T1s + off_); \
            }                                                                  \
            MFMA_HALF(accB, bWs, aT_);                                         \
        }

    LOADW4(bW0, w2base, 0);
    #pragma unroll 1
    for (int kt = 0; kt < 16; kt += 2) {
        LOADW4(bW1, w2base, kt + 1);
        COMPT1(kt, bW0);
        if (kt + 2 < 16) LOADW4(bW0, w2base, kt + 2);
        COMPT1(kt + 1, bW1);
    }

    // epilogue 2: BN + LReLU + 512->2 projection (in-lane over j,r; shfl over hi)
    float p0A[2] = {0.f, 0.f}, p1A[2] = {0.f, 0.f};
    float p0B[2] = {0.f, 0.f}, p1B[2] = {0.f, 0.f};
    #pragma unroll
    for (int j = 0; j < 4; ++j) {
        const int gcol0 = wc * 64 + j * 16 + hi * 4;
        const f32x4 s4 = *reinterpret_cast<const f32x4*>(&sc2[gcol0]);
        const f32x4 h4 = *reinterpret_cast<const f32x4*>(&sh2[gcol0]);
        const f32x4 w0 = *reinterpret_cast<const f32x4*>(&wcf[gcol0]);
        const f32x4 w1 = *reinterpret_cast<const f32x4*>(&wcf[512 + gcol0]);
        #pragma unroll
        for (int i = 0; i < 2; ++i)
            #pragma unroll
            for (int r = 0; r < 4; ++r) {
                float yA = accA[j][i][r] * s4[r] + h4[r];
                yA = yA > 0.f ? yA : 0.1f * yA;
                p0A[i] += yA * w0[r];
                p1A[i] += yA * w1[r];
                float yB = accB[j][i][r] * s4[r] + h4[r];
                yB = yB > 0.f ? yB : 0.1f * yB;
                p0B[i] += yB * w0[r];
                p1B[i] += yB * w1[r];
            }
    }
    __syncthreads();   // Astage reads long done; order before UredF overlay
    #pragma unroll
    for (int i = 0; i < 2; ++i) {
        float a0 = p0A[i], b0 = p1A[i], a1 = p0B[i], b1 = p1B[i];
        a0 += __shfl_xor(a0, 16, 64);  b0 += __shfl_xor(b0, 16, 64);
        a0 += __shfl_xor(a0, 32, 64);  b0 += __shfl_xor(b0, 32, 64);
        a1 += __shfl_xor(a1, 16, 64);  b1 += __shfl_xor(b1, 16, 64);
        a1 += __shfl_xor(a1, 32, 64);  b1 += __shfl_xor(b1, 32, 64);
        if (hi == 0) {
            const int rowA = wr * 64 + i * 16 + rl;
            const int rowB = rowA + 32;
            UredF[(wc * BM + rowA) * 2]     = a0;
            UredF[(wc * BM + rowA) * 2 + 1] = b0;
            UredF[(wc * BM + rowB) * 2]     = a1;
            UredF[(wc * BM + rowB) * 2 + 1] = b1;
        }
    }
    __syncthreads();
    if (tid < BM * 2) {
        const int row = tid >> 1, c = tid & 1;
        float s = 0.f;
        #pragma unroll
        for (int q = 0; q < 8; ++q) s += UredF[(q * BM + row) * 2 + c];
        U[(size_t)(bm * BM + row) * 2 + c] = s;
    }
    #undef COMPT1
}

// ---- GCN on 2-wide features ----
__global__ void gcn_kernel(const float* __restrict__ wn_t, const float* __restrict__ U,
                           const float* __restrict__ bcf, const int* __restrict__ flagp,
                           void* __restrict__ out) {
    const int isbf = *flagp;
    const int wave = threadIdx.x >> 6, lane = threadIdx.x & 63;
    const int task = blockIdx.x * 4 + wave;   // (b, n)
    const int b = task >> 9, n = task & 511;
    const float* wrow = wn_t + n * 512;
    const float* ub = U + b * 1024;
    float a0 = 0.f, a1 = 0.f;
    for (int m = lane; m < 512; m += 64) {
        const float wv = wrow[m];
        a0 += wv * ub[m * 2];
        a1 += wv * ub[m * 2 + 1];
    }
    #pragma unroll
    for (int off = 32; off; off >>= 1) {
        a0 += __shfl_down(a0, off, 64);
        a1 += __shfl_down(a1, off, 64);
    }
    if (lane == 0) {
        const float r0 = a0 + bcf[0];
        const float r1 = a1 + bcf[1];
        if (isbf) {
            ((bf16_t*)out)[task * 2]     = __float2bfloat16(r0);
            ((bf16_t*)out)[task * 2 + 1] = __float2bfloat16(r1);
        } else {
            ((float*)out)[task * 2]     = r0;
            ((float*)out)[task * 2 + 1] = r1;
        }
    }
}

extern "C" void kernel_launch(void* const* d_in, const int* in_sizes, int n_in,
                              void* d_out, int out_size, void* d_ws, size_t ws_size,
                              hipStream_t stream) {
    const void* d   = d_in[0];
    const void* w   = d_in[1];
    const void* W1  = d_in[2];
    const void* b1  = d_in[3];
    const void* g1  = d_in[4];
    const void* be1 = d_in[5];
    const void* m1  = d_in[6];
    const void* v1  = d_in[7];
    const void* W2  = d_in[8];
    const void* b2  = d_in[9];
    const void* g2  = d_in[10];
    const void* be2 = d_in[11];
    const void* m2  = d_in[12];
    const void* v2  = d_in[13];
    const void* Wc  = d_in[14];
    const void* bc  = d_in[15];

    // workspace layout: ~2.6 MB total
    char* ws = (char*)d_ws;
    float*  wn_t = (float*)ws;                         // 1 MB
    bf16_t* W1pk = (bf16_t*)(ws + 0x100000);           // 512 KB (fragment-major)
    bf16_t* W2pk = (bf16_t*)(ws + 0x180000);           // 512 KB
    float*  sc1  = (float*)(ws + 0x200000);
    float*  sh1  = sc1 + 512;
    float*  sc2  = sh1 + 512;
    float*  sh2  = sc2 + 512;
    float*  dinv = sh2 + 512;
    float*  wcf  = (float*)(ws + 0x204000);            // 4 KB
    float*  bcf  = (float*)(ws + 0x205000);
    int*    flag = (int*)(ws + 0x205100);
    float*  U    = (float*)(ws + 0x208000);            // 512 KB

    const int M = 128 * 512;   // 65536 rows

    probe_kernel<<<1, 64, 0, stream>>>(d, flag);
    rowsum_kernel<<<512, 64, 0, stream>>>(w, flag, dinv);
    params_kernel<<<1, 512, 0, stream>>>(g1, b1, m1, v1, be1, g2, b2, m2, v2, be2,
                                         Wc, bc, flag, sc1, sh1, sc2, sh2, wcf, bcf);
    wconv_kernel<<<128, 256, 0, stream>>>(W1, W2, flag, W1pk, W2pk);
    wnorm_kernel<<<1024, 256, 0, stream>>>(w, flag, dinv, wn_t);

    fused_mlp<<<M / BM, 1024, 0, stream>>>(d, W1pk, W2pk,
                                           sc1, sh1, sc2, sh2, wcf, flag, U);

    gcn_kernel<<<M / 4, 256, 0, stream>>>(wn_t, U, bcf, flag, d_out);
}

// Round 13
// 136.171 us; speedup vs baseline: 2.7059x; 1.0090x over previous
//
#include <hip/hip_runtime.h>
#include <hip/hip_bf16.h>

// Sggnn_gcn — fused 2x(Linear512+BN+LReLU) + Wc projection, then GCN on 2-wide
// features. Restructuring: (w_norm^T @ t) @ Wc^T == w_norm^T @ (t @ Wc^T).
// v13 = v12 rebalanced to the measured latencies:
//   * phase 1: SINGLE W set (frees 16 regs; kills v12's 37 MB spill) with
//     load-after-consume placement (L2 latency rides the barrier wait).
//   * phase 1: DEPTH-2 A staging — two named reg sets issued a full round
//     (~800cyc) before their ds_write, matching HBM latency (v12 covered
//     only ~400cyc -> every SWRITE stalled the block at the barrier).
//   * phase 2: unchanged dual-W pipeline (staging regs dead there; fits).

typedef __hip_bfloat16 bf16_t;
typedef __bf16 bf16x8 __attribute__((ext_vector_type(8)));
typedef __bf16 bf16x4 __attribute__((ext_vector_type(4)));
typedef float f32x4 __attribute__((ext_vector_type(4)));

#define KDIM 512
#define BM 128     // rows per block

__device__ __forceinline__ float ldsel(const void* p, int i, int isbf) {
    return isbf ? __bfloat162float(((const bf16_t*)p)[i]) : ((const float*)p)[i];
}

// ---- probe: detect dtype of d (bf16 vs f32) from exponent statistics ----
__global__ void probe_kernel(const void* __restrict__ d, int* __restrict__ flag) {
    const unsigned short* u = (const unsigned short*)d;
    const int l = threadIdx.x;   // 64
    int cnt = 0;
    for (int i = l; i < 256; i += 64) {
        const int e = (u[i] >> 7) & 0xFF;
        cnt += (e >= 118 && e <= 129) ? 1 : 0;
    }
    #pragma unroll
    for (int off = 32; off; off >>= 1) cnt += __shfl_down(cnt, off, 64);
    if (l == 0) *flag = (cnt >= 200) ? 1 : 0;   // bf16 ~255, f32 ~134
}

// ---- prep: rowsum of adj = w + I  ->  d_inv_sqrt ----
__global__ void rowsum_kernel(const void* __restrict__ w, const int* __restrict__ flagp,
                              float* __restrict__ dinv) {
    const int isbf = *flagp;
    const int i = blockIdx.x;
    const int l = threadIdx.x;
    float s = 0.f;
    for (int j = l; j < 512; j += 64) s += ldsel(w, i * 512 + j, isbf);
    #pragma unroll
    for (int off = 32; off; off >>= 1) s += __shfl_down(s, off, 64);
    if (l == 0) dinv[i] = 1.0f / sqrtf(s + 1.0f);
}

// ---- prep: fold BN -> scale/shift; canonicalize Wc, bc to f32 ----
__global__ void params_kernel(const void* g1, const void* b1, const void* m1,
                              const void* v1, const void* be1,
                              const void* g2, const void* b2, const void* m2,
                              const void* v2, const void* be2,
                              const void* Wc, const void* bc,
                              const int* __restrict__ flagp,
                              float* sc1, float* sh1, float* sc2, float* sh2,
                              float* wcf, float* bcf) {
    const int isbf = *flagp;
    const int i = threadIdx.x;  // 512
    float s1 = ldsel(g1, i, isbf) / sqrtf(ldsel(v1, i, isbf) + 1e-5f);
    sc1[i] = s1;
    sh1[i] = (ldsel(b1, i, isbf) - ldsel(m1, i, isbf)) * s1 + ldsel(be1, i, isbf);
    float s2 = ldsel(g2, i, isbf) / sqrtf(ldsel(v2, i, isbf) + 1e-5f);
    sc2[i] = s2;
    sh2[i] = (ldsel(b2, i, isbf) - ldsel(m2, i, isbf)) * s2 + ldsel(be2, i, isbf);
    wcf[i] = ldsel(Wc, i, isbf);
    wcf[512 + i] = ldsel(Wc, 512 + i, isbf);
    if (i < 2) bcf[i] = ldsel(bc, i, isbf);
}

// ---- prep: W1,W2 -> bf16 in FRAGMENT-MAJOR order ----
__global__ void wconv_kernel(const void* __restrict__ W1, const void* __restrict__ W2,
                             const int* __restrict__ flagp,
                             bf16_t* __restrict__ W1pk, bf16_t* __restrict__ W2pk) {
    const int isbf = *flagp;
    const int t = blockIdx.x * 256 + threadIdx.x;   // 0..32767
    const int lane = t & 63;
    const int kt = (t >> 6) & 15;
    const int c16 = t >> 10;
    const int src = (c16 * 16 + (lane & 15)) * 512 + kt * 32 + (lane >> 4) * 8;
    bf16x8 v1, v2;
    #pragma unroll
    for (int e = 0; e < 8; ++e) {
        v1[e] = (__bf16)ldsel(W1, src + e, isbf);
        v2[e] = (__bf16)ldsel(W2, src + e, isbf);
    }
    *reinterpret_cast<bf16x8*>(W1pk + (size_t)t * 8) = v1;
    *reinterpret_cast<bf16x8*>(W2pk + (size_t)t * 8) = v2;
}

// ---- prep: wn_t[n][m] = w_norm[m][n] ----
__global__ void wnorm_kernel(const void* __restrict__ w, const int* __restrict__ flagp,
                             const float* __restrict__ dinv, float* __restrict__ wn_t) {
    const int isbf = *flagp;
    const int idx = blockIdx.x * 256 + threadIdx.x;   // 262144
    const int n = idx >> 9, m = idx & 511;
    float a = ldsel(w, n * 512 + m, isbf) + (m == n ? 1.0f : 0.0f);
    wn_t[idx] = a * dinv[m] * dinv[n];
}

#define JSTRIDE 16384
#define KSTRIDE 1024

#define LOADW4(dst, base, kt)                                                  \
    _Pragma("unroll")                                                          \
    for (int j = 0; j < 4; ++j)                                                \
        dst[j] = *reinterpret_cast<const bf16x8*>((base) + j * JSTRIDE + (kt) * KSTRIDE);

#define MFMA_HALF(accset, bset, aset)                                          \
    _Pragma("unroll")                                                          \
    for (int j = 0; j < 4; ++j)                                                \
        _Pragma("unroll")                                                      \
        for (int i = 0; i < 2; ++i)                                            \
            accset[j][i] = __builtin_amdgcn_mfma_f32_16x16x32_bf16(bset[j], aset[i], accset[j][i], 0, 0, 0);

// issue staging loads for A k-tile kt into named set S (all 1024 threads)
#define SISSUE(S, kt)                                                          \
    {                                                                          \
        if (isbf) sb##S = *reinterpret_cast<const bf16x4*>((const bf16_t*)A + sgbase + (size_t)(kt) * 32); \
        else      sf##S = *reinterpret_cast<const f32x4*>((const float*)A + sgbase + (size_t)(kt) * 32);  \
    }

// convert + ds_write named set S into Astage[bufi] (fragment-major)
#define SWRITE(S, bufi)                                                        \
    {                                                                          \
        bf16x4 v_;                                                             \
        if (isbf) { v_ = sb##S; }                                              \
        else {                                                                 \
            v_[0] = (__bf16)sf##S.x; v_[1] = (__bf16)sf##S.y;                  \
            v_[2] = (__bf16)sf##S.z; v_[3] = (__bf16)sf##S.w;                  \
        }                                                                      \
        *reinterpret_cast<bf16x4*>((char*)Astage + (bufi) * 8192 + sldsoff) = v_; \
    }

// ds_read A frags (2+2 split) + 16 MFMA with the given W set
#define COMPUTE2(bufi, bWs)                                                    \
    {                                                                          \
        const char* ab_ = (const char*)Astage + (bufi) * 8192 + lane * 16;     \
        bf16x8 aT_[2];                                                         \
        aT_[0] = *reinterpret_cast<const bf16x8*>(ab_ + (wr * 4 + 0) * 1024);  \
        aT_[1] = *reinterpret_cast<const bf16x8*>(ab_ + (wr * 4 + 1) * 1024);  \
        MFMA_HALF(accA, bWs, aT_);                                             \
        aT_[0] = *reinterpret_cast<const bf16x8*>(ab_ + (wr * 4 + 2) * 1024);  \
        aT_[1] = *reinterpret_cast<const bf16x8*>(ab_ + (wr * 4 + 3) * 1024);  \
        MFMA_HALF(accB, bWs, aT_);                                             \
    }

// ---- fused MLP: 16 waves, BM=128; depth-2 A staging; phase-1 single-W ----
__launch_bounds__(1024, 4)
__global__ void fused_mlp(const void* __restrict__ A,      // d: f32 or bf16, 65536x512
                          const bf16_t* __restrict__ W1pk, // fragment-major bf16
                          const bf16_t* __restrict__ W2pk,
                          const float* __restrict__ sc1, const float* __restrict__ sh1,
                          const float* __restrict__ sc2, const float* __restrict__ sh2,
                          const float* __restrict__ wcf,   // 1024 f32
                          const int* __restrict__ flagp,
                          float* __restrict__ U)           // 65536 x 2
{
    __shared__ __align__(16) bf16_t T1s[BM * KDIM];      // 128 KB, XOR-swizzled rows
    __shared__ __align__(16) bf16_t Astage[2][BM * 32];  // 2 x 8 KB fragment-major
    float* UredF = (float*)Astage;                       // 8 KB, reused after phase 1

    const int isbf = *flagp;
    const int tid = threadIdx.x;
    const int wave = tid >> 6, lane = tid & 63;
    const int wr = wave >> 3, wc = wave & 7;   // rows wr*64..+64, cols wc*64..+64
    const int bm = blockIdx.x;                 // 0..511; rows bm*128..+128
    const int rl = lane & 15, hi = lane >> 4;

    const char* w1base = (const char*)W1pk + ((size_t)(wc * 4) * 16 * 64 + lane) * 16;
    const char* w2base = (const char*)W2pk + ((size_t)(wc * 4) * 16 * 64 + lane) * 16;

    // staging mapping (ALL 1024 threads): row srow, 4-elem chunk sk4
    const int srow = tid >> 3;                 // 0..127
    const int sk4 = tid & 7;                   // 0..7 (4 elems each)
    const size_t sgbase = (size_t)(bm * BM + srow) * KDIM + sk4 * 4;
    const int sldsoff = (srow >> 4) * 1024 + ((srow & 15) + (sk4 >> 1) * 16) * 16
                        + (sk4 & 1) * 8;

    f32x4 accA[4][2] = {}, accB[4][2] = {};
    bf16x8 bW[4];
    f32x4 sfA, sfB;
    bf16x4 sbA, sbB;

    // ================= phase 1: T1 = lrelu(bn1(A @ W1^T)) =================
    SISSUE(A, 0);
    SWRITE(A, 0);         // buf0 <- kt0
    SISSUE(A, 1);         // kt1 in flight (written end of body0)
    SISSUE(B, 2);         // kt2 in flight (written end of body1) — depth 2
    LOADW4(bW, w1base, 0);
    __syncthreads();      // buf0 visible

    #pragma unroll 1
    for (int kt = 0; kt < 16; kt += 2) {
        // ---- body0: compute kt from buf[kt&1] with bW(kt) ----
        COMPUTE2(kt & 1, bW);
        LOADW4(bW, w1base, kt + 1);            // W for kt+1 (rides barrier wait)
        SWRITE(A, (kt + 1) & 1);               // sA = kt+1, issued 1 round ago
        if (kt + 3 < 16) SISSUE(A, kt + 3);    // re-arm sA, lands in ~1 round
        __syncthreads();
        // ---- body1: compute kt+1 from buf[(kt+1)&1] with bW(kt+1) ----
        COMPUTE2((kt + 1) & 1, bW);
        if (kt + 2 < 16) {
            LOADW4(bW, w1base, kt + 2);
            SWRITE(B, (kt + 2) & 1);           // sB = kt+2, issued 1 round ago
        }
        if (kt + 4 < 16) SISSUE(B, kt + 4);    // re-arm sB
        __syncthreads();
    }

    // epilogue 1: BN + LReLU; lane holds 4 ADJACENT out-cols -> b64 store
    #pragma unroll
    for (int j = 0; j < 4; ++j) {
        const int gcol0 = wc * 64 + j * 16 + hi * 4;
        const f32x4 s4 = *reinterpret_cast<const f32x4*>(&sc1[gcol0]);
        const f32x4 h4 = *reinterpret_cast<const f32x4*>(&sh1[gcol0]);
        #pragma unroll
        for (int h = 0; h < 2; ++h)
            #pragma unroll
            for (int i = 0; i < 2; ++i) {
                const int row = wr * 64 + h * 32 + i * 16 + rl;
                int off = (row << 10) + (gcol0 << 1);
                off ^= (row & 7) << 4;
                const f32x4 av = h ? accB[j][i] : accA[j][i];
                bf16x4 pk;
                #pragma unroll
                for (int r = 0; r < 4; ++r) {
                    float y = av[r] * s4[r] + h4[r];
                    y = y > 0.f ? y : 0.1f * y;
                    pk[r] = (__bf16)y;
                }
                *reinterpret_cast<bf16x4*>((char*)T1s + off) = pk;
            }
    }
    __syncthreads();

    // ================= phase 2: Y2 = lrelu(bn2(T1 @ W2^T)); U = Y2 @ Wc^T =================
    #pragma unroll
    for (int j = 0; j < 4; ++j)
        #pragma unroll
        for (int i = 0; i < 2; ++i) {
            accA[j][i] = f32x4{0.f, 0.f, 0.f, 0.f};
            accB[j][i] = f32x4{0.f, 0.f, 0.f, 0.f};
        }

    // T1s frag read (2+2 split) + 16 MFMA with given W set
    #define COMPT1(kt, bWs)                                                    \
        {                                                                      \
            bf16x8 aT_[2];                                                     \
            _Pragma("unroll")                                                  \
            for (int i = 0; i < 2; ++i) {                                      \
                const int row_ = wr * 64 + i * 16 + rl;                        \
                int off_ = (row_ << 10) + (kt) * 64 + hi * 16;                 \
                off_ ^= (row_ & 7) << 4;                                       \
                aT_[i] = *reinterpret_cast<const bf16x8*>((const char*)T1s + off_); \
            }                                                                  \
            MFMA_HALF(accA, bWs, aT_);                                         \
            _Pragma("unroll")                                                  \
            for (int i = 0; i < 2; ++i) {                                      \
                const int row_ = wr * 64 + 32 + i * 16 + rl;                   \
                int off_ = (row_ << 10) + (kt) * 64 + hi * 16;                 \
                off_ ^= (row_ & 7) << 4;                                       \
                aT_[i] = *reinterpret_cast<const bf16x8*>((const char*)T1s + off_); \
            }                                                                  \
            MFMA_HALF(accB, bWs, aT_);                                         \
        }

    {
        bf16x8 bW1s[4];
        LOADW4(bW, w2base, 0);
        #pragma unroll 1
        for (int kt = 0; kt < 16; kt += 2) {
            LOADW4(bW1s, w2base, kt + 1);
            COMPT1(kt, bW);
            if (kt + 2 < 16) LOADW4(bW, w2base, kt + 2);
            COMPT1(kt + 1, bW1s);
        }
    }

    // epilogue 2: BN + LReLU + 512->2 projection (in-lane over j,r; shfl over hi)
    float p0A[2] = {0.f, 0.f}, p1A[2] = {0.f, 0.f};
    float p0B[2] = {0.f, 0.f}, p1B[2] = {0.f, 0.f};
    #pragma unroll
    for (int j = 0; j < 4; ++j) {
        const int gcol0 = wc * 64 + j * 16 + hi * 4;
        const f32x4 s4 = *reinterpret_cast<const f32x4*>(&sc2[gcol0]);
        const f32x4 h4 = *reinterpret_cast<const f32x4*>(&sh2[gcol0]);
        const f32x4 w0 = *reinterpret_cast<const f32x4*>(&wcf[gcol0]);
        const f32x4 w1 = *reinterpret_cast<const f32x4*>(&wcf[512 + gcol0]);
        #pragma unroll
        for (int i = 0; i < 2; ++i)
            #pragma unroll
            for (int r = 0; r < 4; ++r) {
                float yA = accA[j][i][r] * s4[r] + h4[r];
                yA = yA > 0.f ? yA : 0.1f * yA;
                p0A[i] += yA * w0[r];
                p1A[i] += yA * w1[r];
                float yB = accB[j][i][r] * s4[r] + h4[r];
                yB = yB > 0.f ? yB : 0.1f * yB;
                p0B[i] += yB * w0[r];
                p1B[i] += yB * w1[r];
            }
    }
    __syncthreads();   // Astage reads long done; order before UredF overlay
    #pragma unroll
    for (int i = 0; i < 2; ++i) {
        float a0 = p0A[i], b0 = p1A[i], a1 = p0B[i], b1 = p1B[i];
        a0 += __shfl_xor(a0, 16, 64);  b0 += __shfl_xor(b0, 16, 64);
        a0 += __shfl_xor(a0, 32, 64);  b0 += __shfl_xor(b0, 32, 64);
        a1 += __shfl_xor(a1, 16, 64);  b1 += __shfl_xor(b1, 16, 64);
        a1 += __shfl_xor(a1, 32, 64);  b1 += __shfl_xor(b1, 32, 64);
        if (hi == 0) {
            const int rowA = wr * 64 + i * 16 + rl;
            const int rowB = rowA + 32;
            UredF[(wc * BM + rowA) * 2]     = a0;
            UredF[(wc * BM + rowA) * 2 + 1] = b0;
            UredF[(wc * BM + rowB) * 2]     = a1;
            UredF[(wc * BM + rowB) * 2 + 1] = b1;
        }
    }
    __syncthreads();
    if (tid < BM * 2) {
        const int row = tid >> 1, c = tid & 1;
        float s = 0.f;
        #pragma unroll
        for (int q = 0; q < 8; ++q) s += UredF[(q * BM + row) * 2 + c];
        U[(size_t)(bm * BM + row) * 2 + c] = s;
    }
    #undef COMPT1
}

// ---- GCN on 2-wide features ----
__global__ void gcn_kernel(const float* __restrict__ wn_t, const float* __restrict__ U,
                           const float* __restrict__ bcf, const int* __restrict__ flagp,
                           void* __restrict__ out) {
    const int isbf = *flagp;
    const int wave = threadIdx.x >> 6, lane = threadIdx.x & 63;
    const int task = blockIdx.x * 4 + wave;   // (b, n)
    const int b = task >> 9, n = task & 511;
    const float* wrow = wn_t + n * 512;
    const float* ub = U + b * 1024;
    float a0 = 0.f, a1 = 0.f;
    for (int m = lane; m < 512; m += 64) {
        const float wv = wrow[m];
        a0 += wv * ub[m * 2];
        a1 += wv * ub[m * 2 + 1];
    }
    #pragma unroll
    for (int off = 32; off; off >>= 1) {
        a0 += __shfl_down(a0, off, 64);
        a1 += __shfl_down(a1, off, 64);
    }
    if (lane == 0) {
        const float r0 = a0 + bcf[0];
        const float r1 = a1 + bcf[1];
        if (isbf) {
            ((bf16_t*)out)[task * 2]     = __float2bfloat16(r0);
            ((bf16_t*)out)[task * 2 + 1] = __float2bfloat16(r1);
        } else {
            ((float*)out)[task * 2]     = r0;
            ((float*)out)[task * 2 + 1] = r1;
        }
    }
}

extern "C" void kernel_launch(void* const* d_in, const int* in_sizes, int n_in,
                              void* d_out, int out_size, void* d_ws, size_t ws_size,
                              hipStream_t stream) {
    const void* d   = d_in[0];
    const void* w   = d_in[1];
    const void* W1  = d_in[2];
    const void* b1  = d_in[3];
    const void* g1  = d_in[4];
    const void* be1 = d_in[5];
    const void* m1  = d_in[6];
    const void* v1  = d_in[7];
    const void* W2  = d_in[8];
    const void* b2  = d_in[9];
    const void* g2  = d_in[10];
    const void* be2 = d_in[11];
    const void* m2  = d_in[12];
    const void* v2  = d_in[13];
    const void* Wc  = d_in[14];
    const void* bc  = d_in[15];

    // workspace layout: ~2.6 MB total
    char* ws = (char*)d_ws;
    float*  wn_t = (float*)ws;                         // 1 MB
    bf16_t* W1pk = (bf16_t*)(ws + 0x100000);           // 512 KB (fragment-major)
    bf16_t* W2pk = (bf16_t*)(ws + 0x180000);           // 512 KB
    float*  sc1  = (float*)(ws + 0x200000);
    float*  sh1  = sc1 + 512;
    float*  sc2  = sh1 + 512;
    float*  sh2  = sc2 + 512;
    float*  dinv = sh2 + 512;
    float*  wcf  = (float*)(ws + 0x204000);            // 4 KB
    float*  bcf  = (float*)(ws + 0x205000);
    int*    flag = (int*)(ws + 0x205100);
    float*  U    = (float*)(ws + 0x208000);            // 512 KB

    const int M = 128 * 512;   // 65536 rows

    probe_kernel<<<1, 64, 0, stream>>>(d, flag);
    rowsum_kernel<<<512, 64, 0, stream>>>(w, flag, dinv);
    params_kernel<<<1, 512, 0, stream>>>(g1, b1, m1, v1, be1, g2, b2, m2, v2, be2,
                                         Wc, bc, flag, sc1, sh1, sc2, sh2, wcf, bcf);
    wconv_kernel<<<128, 256, 0, stream>>>(W1, W2, flag, W1pk, W2pk);
    wnorm_kernel<<<1024, 256, 0, stream>>>(w, flag, dinv, wn_t);

    fused_mlp<<<M / BM, 1024, 0, stream>>>(d, W1pk, W2pk,
                                           sc1, sh1, sc2, sh2, wcf, flag, U);

    gcn_kernel<<<M / 4, 256, 0, stream>>>(wn_t, U, bcf, flag, d_out);
}